// Round 7
// baseline (867.032 us; speedup 1.0000x reference)
//
#include <hip/hip_runtime.h>
#include <hip/hip_bf16.h>

// ---------------------------------------------------------------------------
// CorrectTransformerAdaptor — Round 11: pipelined GEMM + attn async-stage.
//   Round-6 evidence: attn not HBM-bound (FETCH 139->24.6MB, dur ~same);
//   GEMM aggregate ~60% of wall at ~400-450 TF (1-phase 128² structure).
//   - gemm256: BM=256/BN=128/BK=32, 512thr/8 waves, double-buffered LDS
//     (48KB), T3-min 2-phase: prefetch K-tile t+1 via global_load_lds
//     BEFORE computing tile t; ONE barrier per K-step. BK=32 XOR swizzle
//     (chunk ^ ((row>>1)&3)) on both source and read -> 2-way (free).
//     __launch_bounds__(512,4) caps VGPR <=128 -> 2 blocks/CU.
//     Used for the 5 big GEMMs; F1/F2 stay on the 128² kernel.
//   - attn: T14 async-STAGE — K/V tile kt+1 loaded into ping-pong regs
//     before compute of kt (2x-unrolled, named regs); ds_write from landed
//     regs after the barrier. Math/swizzles/T13 unchanged.
// ---------------------------------------------------------------------------

#define DMODEL 1024
#define DFF 2048
#define FHID 256
#define NHEAD 8
#define DKH 128
#define TSEQ 1024

typedef __hip_bfloat16 bf16;
typedef __attribute__((ext_vector_type(8))) short bf16x8;   // 8 bf16 = 4 VGPR
typedef __attribute__((ext_vector_type(4))) float f32x4;

#define MFMA16(a, b, c) __builtin_amdgcn_mfma_f32_16x16x32_bf16(a, b, c, 0, 0, 0)

__device__ int g_is_bf16;

// one coherent load per block, broadcast via LDS (needs all threads at entry)
__device__ __forceinline__ bool flagbf_block() {
    __shared__ int fsh;
    if (threadIdx.x == 0)
        fsh = __hip_atomic_load(&g_is_bf16, __ATOMIC_ACQUIRE,
                                __HIP_MEMORY_SCOPE_AGENT);
    __syncthreads();
    return fsh != 0;
}
__device__ __forceinline__ float gload(const void* p, size_t i, bool bf) {
    return bf ? __bfloat162float(((const bf16*)p)[i]) : ((const float*)p)[i];
}
__device__ __forceinline__ void gstore(void* p, size_t i, bool bf, float v) {
    if (bf) ((bf16*)p)[i] = __float2bfloat16(v);
    else    ((float*)p)[i] = v;
}

// direct global->LDS, 16 bytes/lane. LDS base must be wave-uniform (m104);
// lane writes at base + lane*16. Global address is per-lane.
__device__ __forceinline__ void async16(const bf16* g, const bf16* l) {
    __builtin_amdgcn_global_load_lds(
        (const __attribute__((address_space(1))) void*)g,
        (__attribute__((address_space(3))) void*)l, 16, 0, 0);
}

// ---- dtype probe (64 lanes, ballot) ---------------------------------------
__global__ void detect_kernel(const void* __restrict__ probe) {
    const int lane = threadIdx.x & 63;
    const bf16* h = (const bf16*)probe;
    int ok = 1;
    #pragma unroll
    for (int j = 0; j < 4; ++j) {
        float v = __bfloat162float(h[lane * 4 + j]);
        if (!(fabsf(v) <= 1000.0f)) ok = 0;   // catches huge AND NaN
    }
    unsigned long long m = __ballot(ok);
    if (lane == 0)
        __hip_atomic_store(&g_is_bf16, m == ~0ull ? 1 : 0, __ATOMIC_RELEASE,
                           __HIP_MEMORY_SCOPE_AGENT);
}

// ---- weight arena offsets (bf16 elems) — fp32-input path only -------------
#define O_W1  0ull
#define O_W2  2097152ull
#define O_QK  4194304ull
#define O_WV  8388608ull
#define O_WO  10485760ull
#define O_F1  12582912ull
#define O_F2  13107200ull
#define ARENA_ELEMS 13631488ull

// one block = 16384 elems; per iteration a wave does unit-stride float4
// reads (1KB/instr) and unit-stride uint2 bf16 writes (512B/instr).
__global__ __launch_bounds__(256) void cvt_weights(
        const void* W1, const void* W2, const void* Wq, const void* Wk,
        const void* Wv, const void* Wo, const void* F1, const void* F2,
        bf16* __restrict__ arena) {
    if (flagbf_block()) return;   // bf16 inputs: GEMMs read them directly
    int b = blockIdx.x;
    const float* src; bf16* dst;
    if      (b < 128)  {           src = (const float*)W1 + (size_t)b * 16384;
                         dst = arena + O_W1 + (size_t)b * 16384; }
    else if (b < 256)  { b -= 128; src = (const float*)W2 + (size_t)b * 16384;
                         dst = arena + O_W2 + (size_t)b * 16384; }
    else if (b < 384)  { b -= 256; src = (const float*)Wq + (size_t)b * 16384;
                         dst = arena + O_QK + (size_t)(b >> 6) * 2097152
                                            + (size_t)(b & 63) * 16384; }
    else if (b < 512)  { b -= 384; src = (const float*)Wk + (size_t)b * 16384;
                         dst = arena + O_QK + (size_t)(b >> 6) * 2097152
                                            + 1048576 + (size_t)(b & 63) * 16384; }
    else if (b < 640)  { b -= 512; src = (const float*)Wv + (size_t)b * 16384;
                         dst = arena + O_WV + (size_t)b * 16384; }
    else if (b < 768)  { b -= 640; src = (const float*)Wo + (size_t)b * 16384;
                         dst = arena + O_WO + (size_t)b * 16384; }
    else if (b < 800)  { b -= 768; src = (const float*)F1 + (size_t)b * 16384;
                         dst = arena + O_F1 + (size_t)b * 16384; }
    else               { b -= 800; src = (const float*)F2 + (size_t)b * 16384;
                         dst = arena + O_F2 + (size_t)b * 16384; }
    const int tid = threadIdx.x;
    #pragma unroll
    for (int it = 0; it < 16; ++it) {
        const int e = it * 1024 + tid * 4;
        float4 f = *(const float4*)(src + e);
        bf16 t[4] = {__float2bfloat16(f.x), __float2bfloat16(f.y),
                     __float2bfloat16(f.z), __float2bfloat16(f.w)};
        *(uint2*)(dst + e) = *(const uint2*)t;
    }
}

__global__ __launch_bounds__(256) void cvt_x(
        const void* __restrict__ X, size_t x_off, bf16* __restrict__ dst) {
    if (flagbf_block()) return;   // bf16 x is consumed in place
    const float* src = (const float*)X + x_off + (size_t)blockIdx.x * 16384;
    bf16* d = dst + (size_t)blockIdx.x * 16384;
    const int tid = threadIdx.x;
    #pragma unroll
    for (int it = 0; it < 16; ++it) {
        const int e = it * 1024 + tid * 4;
        float4 f = *(const float4*)(src + e);
        bf16 t[4] = {__float2bfloat16(f.x), __float2bfloat16(f.y),
                     __float2bfloat16(f.z), __float2bfloat16(f.w)};
        *(uint2*)(d + e) = *(const uint2*)t;
    }
}

// ---------------- 256x128 2-phase GEMM: C[M,N] = op(A @ W^T + b) -----------
// 512 thr = 8 waves (4M x 2N), per-wave 64x64 out, BK=32, dbuf LDS 48KB.
// Prefetch next K-tile (global_load_lds) issued BEFORE compute; one barrier
// per K-step. BK=32 swizzle: chunk pos = want ^ ((row>>1)&3), pre-swizzled
// global source, matching XOR on read (2-way = free).
template <bool RELU, bool ADD, int CMODE, bool TRANSC, bool BIAS2>
__global__ __launch_bounds__(512, 4) void gemm256(
        const bf16* Abf, const bf16* Acv,
        const bf16* Wlo_bf, const bf16* Whi_bf,
        const bf16* Wlo_cv, const bf16* Whi_cv,
        const void* __restrict__ bias, const void* __restrict__ bias2,
        size_t b_off,
        void* __restrict__ C, size_t c_off,
        int M, int N, int K) {
    const bool fl = flagbf_block();
    const bf16* A   = fl ? Abf : Acv;
    const bf16* Wlo = fl ? Wlo_bf : Wlo_cv;
    const bf16* Whi = fl ? Whi_bf : Whi_cv;

    __shared__ __align__(16) bf16 As[2][256 * 32];   // 32 KB
    __shared__ __align__(16) bf16 Bs[2][128 * 32];   // 16 KB

    // XCD band remap over (gx = N/128, gy = M/256)
    const int gx = gridDim.x;
    const int lin = blockIdx.x + gx * blockIdx.y;
    int bm, bn;
    if ((gridDim.y & 7) == 0) {
        const int xcd = lin & 7, j = lin >> 3;
        const int rpx = gridDim.y >> 3;
        bm = (xcd * rpx + (j / gx)) * 256;
        bn = (j % gx) * 128;
    } else {
        bm = blockIdx.y * 256;
        bn = blockIdx.x * 128;
    }

    const int tid = threadIdx.x;
    const int wave = tid >> 6, lane = tid & 63;
    const int quad = lane >> 4, l15 = lane & 15;
    const int wm = wave >> 1, wn = wave & 1;

    const bf16* Wp;
    int bnr;
    if (BIAS2 && bn >= 1024) { Wp = Whi; bnr = bn - 1024; }
    else                     { Wp = Wlo; bnr = bn; }

    // staging: lane covers row lane>>2 (of 16), chunk lane&3; source chunk
    // pre-swizzled by ((row>>1)&3) == ((lane>>3)&3) for 16-aligned bases.
    const int srow = lane >> 2;
    const int schunk = (lane & 3) ^ ((lane >> 3) & 3);
    const bf16* gaBase = A  + (size_t)(bm  + wave * 32 + srow) * K + schunk * 8;
    const bf16* gbBase = Wp + (size_t)(bnr + wave * 16 + srow) * K + schunk * 8;
    const int laOff0 = (wave * 32) * 32;
    const int laOff1 = (wave * 32 + 16) * 32;
    const int lbOff  = (wave * 16) * 32;

    f32x4 acc[4][4];
    #pragma unroll
    for (int i = 0; i < 4; ++i)
        #pragma unroll
        for (int j = 0; j < 4; ++j) acc[i][j] = (f32x4){0.f, 0.f, 0.f, 0.f};

    const int nt = K >> 5;
    int cur = 0;

    // prologue: stage K-tile 0 into buf 0
    async16(gaBase, &As[0][laOff0]);
    async16(gaBase + (size_t)16 * K, &As[0][laOff1]);
    async16(gbBase, &Bs[0][lbOff]);
    __asm__ __volatile__("s_waitcnt vmcnt(0)" ::: "memory");
    __syncthreads();

    for (int t = 0; t < nt; ++t) {
        if (t + 1 < nt) {                       // prefetch next tile
            const int kn = (t + 1) << 5;
            async16(gaBase + kn, &As[cur ^ 1][laOff0]);
            async16(gaBase + (size_t)16 * K + kn, &As[cur ^ 1][laOff1]);
            async16(gbBase + kn, &Bs[cur ^ 1][lbOff]);
        }
        // compute on buf cur
        bf16x8 bfr[4];
        #pragma unroll
        for (int ni = 0; ni < 4; ++ni) {
            const int row = wn * 64 + ni * 16 + l15;
            bfr[ni] = *(const bf16x8*)
                &Bs[cur][row * 32 + ((quad ^ ((row >> 1) & 3)) << 3)];
        }
        #pragma unroll
        for (int mi = 0; mi < 4; ++mi) {
            const int row = wm * 64 + mi * 16 + l15;
            bf16x8 af = *(const bf16x8*)
                &As[cur][row * 32 + ((quad ^ ((row >> 1) & 3)) << 3)];
            #pragma unroll
            for (int ni = 0; ni < 4; ++ni)
                acc[mi][ni] = MFMA16(af, bfr[ni], acc[mi][ni]);
        }
        __syncthreads();   // reads done + (compiler vmcnt drain) prefetch landed
        cur ^= 1;
    }

    // epilogue: acc row = quad*4+rr, col = lane&15 (verified m89/m91 layout)
    const bool cbf = CMODE ? fl : true;
    #pragma unroll
    for (int ni = 0; ni < 4; ++ni) {
        const int col = bn + wn * 64 + ni * 16 + l15;
        float bv;
        if (BIAS2) bv = col < 1024 ? gload(bias, b_off + col, fl)
                                   : gload(bias2, b_off + col - 1024, fl);
        else       bv = gload(bias, b_off + col, fl);
        #pragma unroll
        for (int mi = 0; mi < 4; ++mi) {
            const int row0 = bm + wm * 64 + mi * 16 + quad * 4;
            if (TRANSC) {
                bf16 pk[4];
                #pragma unroll
                for (int rr = 0; rr < 4; ++rr)
                    pk[rr] = __float2bfloat16(acc[mi][ni][rr] + bv);
                *(uint2*)((bf16*)C + c_off + (size_t)col * M + row0) =
                    *(const uint2*)pk;
            } else {
                #pragma unroll
                for (int rr = 0; rr < 4; ++rr) {
                    float v = acc[mi][ni][rr] + bv;
                    if (RELU) v = fmaxf(v, 0.f);
                    size_t idx = c_off + (size_t)(row0 + rr) * N + col;
                    if (ADD) v += gload(C, idx, cbf);
                    gstore(C, idx, cbf, v);
                }
            }
        }
    }
}

// ---------------- 128x128 m97 GEMM (kept for F1/F2) ------------------------
template <bool RELU, bool ADD, int CMODE, bool TRANSC, bool BIAS2>
__global__ __launch_bounds__(256) void gemm_bf16(
        const bf16* Abf, const bf16* Acv,
        const bf16* Wlo_bf, const bf16* Whi_bf,
        const bf16* Wlo_cv, const bf16* Whi_cv,
        const void* __restrict__ bias, const void* __restrict__ bias2,
        size_t b_off,
        void* __restrict__ C, size_t c_off,
        int M, int N, int K) {
    const bool fl = flagbf_block();
    const bf16* A   = fl ? Abf : Acv;
    const bf16* Wlo = fl ? Wlo_bf : Wlo_cv;
    const bf16* Whi = fl ? Whi_bf : Whi_cv;

    __shared__ __align__(16) bf16 As[128 * 64];
    __shared__ __align__(16) bf16 Bs[128 * 64];

    const int gx = gridDim.x;
    const int lin = blockIdx.x + gx * blockIdx.y;
    int bm, bn;
    if ((gridDim.y & 7) == 0) {
        const int xcd = lin & 7, j = lin >> 3;
        const int rpx = gridDim.y >> 3;
        bm = (xcd * rpx + j / gx) * 128;
        bn = (j % gx) * 128;
    } else {
        bm = blockIdx.y * 128;
        bn = blockIdx.x * 128;
    }

    const int tid = threadIdx.x;
    const int wave = tid >> 6, lane = tid & 63;
    const int quad = lane >> 4, l15 = lane & 15;
    const int wr = wave >> 1, wc = wave & 1;
    const int l8 = lane >> 3, l7 = lane & 7;
    const int swz = l7 ^ l8;          // row&7 == l8 for our staging rows

    const bf16* Wp;
    int bnr;
    if (BIAS2 && bn >= 1024) { Wp = Whi; bnr = bn - 1024; }
    else                     { Wp = Wlo; bnr = bn; }

    f32x4 acc[4][4];
    #pragma unroll
    for (int i = 0; i < 4; ++i)
        #pragma unroll
        for (int j2 = 0; j2 < 4; ++j2) acc[i][j2] = (f32x4){0.f, 0.f, 0.f, 0.f};

    const bf16* ga0 = A  + (size_t)(bm  + wave * 32 + l8) * K + swz * 8;
    const bf16* gb0 = Wp + (size_t)(bnr + wave * 32 + l8) * K + swz * 8;
    bf16* la0 = &As[(wave * 32) * 64];
    bf16* lb0 = &Bs[(wave * 32) * 64];

    for (int k0 = 0; k0 < K; k0 += 64) {
        __syncthreads();
        #pragma unroll
        for (int i = 0; i < 4; ++i) {
            async16(ga0 + (size_t)(i * 8) * K + k0, la0 + i * 512);
            async16(gb0 + (size_t)(i * 8) * K + k0, lb0 + i * 512);
        }
        __syncthreads();

        #pragma unroll
        for (int ks = 0; ks < 2; ++ks) {
            bf16x8 af[4], bfr[4];
            #pragma unroll
            for (int mi = 0; mi < 4; ++mi) {
                const int row = wr * 64 + mi * 16 + l15;
                af[mi] = *(const bf16x8*)
                    &As[row * 64 + ((((ks << 2) | quad) ^ (row & 7)) << 3)];
            }
            #pragma unroll
            for (int ni = 0; ni < 4; ++ni) {
                const int row = wc * 64 + ni * 16 + l15;
                bfr[ni] = *(const bf16x8*)
                    &Bs[row * 64 + ((((ks << 2) | quad) ^ (row & 7)) << 3)];
            }
            #pragma unroll
            for (int mi = 0; mi < 4; ++mi)
                #pragma unroll
                for (int ni = 0; ni < 4; ++ni)
                    acc[mi][ni] = MFMA16(af[mi], bfr[ni], acc[mi][ni]);
        }
    }

    const bool cbf = CMODE ? fl : true;
    #pragma unroll
    for (int ni = 0; ni < 4; ++ni) {
        const int col = bn + wc * 64 + ni * 16 + l15;
        float bv;
        if (BIAS2) bv = col < 1024 ? gload(bias, b_off + col, fl)
                                   : gload(bias2, b_off + col - 1024, fl);
        else       bv = gload(bias, b_off + col, fl);
        #pragma unroll
        for (int mi = 0; mi < 4; ++mi) {
            const int row0 = bm + wr * 64 + mi * 16 + quad * 4;
            if (TRANSC) {
                bf16 pk[4];
                #pragma unroll
                for (int rr = 0; rr < 4; ++rr)
                    pk[rr] = __float2bfloat16(acc[mi][ni][rr] + bv);
                *(uint2*)((bf16*)C + c_off + (size_t)col * M + row0) =
                    *(const uint2*)pk;
            } else {
                #pragma unroll
                for (int rr = 0; rr < 4; ++rr) {
                    float v = acc[mi][ni][rr] + bv;
                    if (RELU) v = fmaxf(v, 0.f);
                    size_t idx = c_off + (size_t)(row0 + rr) * N + col;
                    if (ADD) v += gload(C, idx, cbf);
                    gstore(C, idx, cbf, v);
                }
            }
        }
    }
}

// ---------------- LayerNorm: one wave per row, shuffle-only ----------------
__global__ __launch_bounds__(256) void ln_wave(
        const void* __restrict__ X, size_t x_off,
        const void* __restrict__ g, const void* __restrict__ b, size_t gb_off,
        bf16* __restrict__ H) {
    const bool fl = flagbf_block();
    const int lane = threadIdx.x & 63;
    const int row = blockIdx.x * 4 + (threadIdx.x >> 6);
    const size_t xrow = x_off + (size_t)row * DMODEL;

    float v[16];
    if (fl) {
        const bf16* xp = (const bf16*)X + xrow;
        #pragma unroll
        for (int c = 0; c < 2; ++c) {
            uint4 raw = *(const uint4*)(xp + c * 512 + lane * 8);
            const bf16* rb = (const bf16*)&raw;
            #pragma unroll
            for (int j = 0; j < 8; ++j) v[c * 8 + j] = __bfloat162float(rb[j]);
        }
    } else {
        const float* xp = (const float*)X + xrow;
        #pragma unroll
        for (int c = 0; c < 4; ++c) {
            float4 f = *(const float4*)(xp + c * 256 + lane * 4);
            v[c * 4 + 0] = f.x; v[c * 4 + 1] = f.y;
            v[c * 4 + 2] = f.z; v[c * 4 + 3] = f.w;
        }
    }

    float s = 0.f;
    #pragma unroll
    for (int j = 0; j < 16; ++j) s += v[j];
    #pragma unroll
    for (int off = 32; off > 0; off >>= 1) s += __shfl_xor(s, off);
    const float mean = s * (1.f / DMODEL);

    float vs = 0.f;
    #pragma unroll
    for (int j = 0; j < 16; ++j) { float d = v[j] - mean; vs += d * d; }
    #pragma unroll
    for (int off = 32; off > 0; off >>= 1) vs += __shfl_xor(vs, off);
    const float rstd = rsqrtf(vs * (1.f / DMODEL) + 1e-12f);

    bf16* h = H + (size_t)row * DMODEL;
    if (fl) {
        const bf16* gp = (const bf16*)g + gb_off;
        const bf16* bp = (const bf16*)b + gb_off;
        #pragma unroll
        for (int c = 0; c < 2; ++c) {
            const int o = c * 512 + lane * 8;
            uint4 gr = *(const uint4*)(gp + o);
            uint4 br = *(const uint4*)(bp + o);
            const bf16* gg = (const bf16*)&gr;
            const bf16* bb = (const bf16*)&br;
            bf16 outv[8];
            #pragma unroll
            for (int j = 0; j < 8; ++j)
                outv[j] = __float2bfloat16((v[c * 8 + j] - mean) * rstd *
                          __bfloat162float(gg[j]) + __bfloat162float(bb[j]));
            *(uint4*)(h + o) = *(const uint4*)outv;
        }
    } else {
        const float* gp = (const float*)g + gb_off;
        const float* bp = (const float*)b + gb_off;
        #pragma unroll
        for (int c = 0; c < 4; ++c) {
            const int o = c * 256 + lane * 4;
            float4 gr = *(const float4*)(gp + o);
            float4 br = *(const float4*)(bp + o);
            const float gg[4] = {gr.x, gr.y, gr.z, gr.w};
            const float bb[4] = {br.x, br.y, br.z, br.w};
            bf16 outv[4];
            #pragma unroll
            for (int j = 0; j < 4; ++j)
                outv[j] = __float2bfloat16((v[c * 4 + j] - mean) * rstd * gg[j] + bb[j]);
            *(uint2*)(h + o) = *(const uint2*)outv;
        }
    }
}

// ---------------- Flash-style MFMA attention -------------------------------
// Grid: (TSEQ/128, NHEAD, c). Block: 512 threads = 8 waves.
// T14 async-STAGE: K/V tile kt+1 prefetched into ping-pong regs before
// compute of kt; ds_write from landed regs. XCD group swizzle kept.
__global__ __launch_bounds__(512) void attn_mfma(
        const bf16* __restrict__ QK, const bf16* __restrict__ Vg,
        bf16* __restrict__ Om) {
    const int cch = (int)gridDim.z;                  // chunk count c
    const int lin = blockIdx.x + (int)gridDim.x *
                    (blockIdx.y + (int)gridDim.y * blockIdx.z);
    const int xcd = lin & 7, j = lin >> 3;
    const int qt = j & 7, gl = j >> 3;
    const int g = xcd * cch + gl;
    const int h = g & 7, bb = g >> 3;

    const int Mc = cch * TSEQ;
    const int tid = threadIdx.x;
    const int wave = tid >> 6, lane = tid & 63;
    const int quad = lane >> 4, l15 = lane & 15;

    __shared__ __align__(16) bf16 Kt[64][128];
    __shared__ __align__(16) bf16 Vt[128][64];
    __shared__ __align__(16) bf16 Ps[8][16][72];

    const int qrow = qt * 128 + wave * 16 + l15;
    const float scale = 0.08838834764831845f;  // 1/sqrt(128)

    bf16x8 qf[4];
    #pragma unroll
    for (int kc = 0; kc < 4; ++kc) {
        uint4 raw = *(const uint4*)(QK + (size_t)(bb * TSEQ + qrow) * 2048 +
                                    h * DKH + kc * 32 + quad * 8);
        const bf16* rb = (const bf16*)&raw;
        bf16 tmp[8];
        #pragma unroll
        for (int j2 = 0; j2 < 8; ++j2)
            tmp[j2] = __float2bfloat16(__bfloat162float(rb[j2]) * scale);
        qf[kc] = *(const bf16x8*)tmp;
    }

    f32x4 o[8];
    #pragma unroll
    for (int i = 0; i < 8; ++i) o[i] = (f32x4){0.f, 0.f, 0.f, 0.f};
    float m_i[4] = {-1e30f, -1e30f, -1e30f, -1e30f};
    float l_i[4] = {0.f, 0.f, 0.f, 0.f};

    const int skey = tid >> 3;              // K staging: row = key (0..63)
    const int dseg = (tid & 7) * 16;        // 2 x uint4 per thread
    const int sk7 = skey & 7;
    const int vd = tid >> 2;                // V staging: row = d (0..127)
    const int vseg = (tid & 3) * 16;        // 2 x uint4 per thread

    const bf16* kRow = QK + (size_t)(bb * TSEQ + skey) * 2048 + 1024 +
                       h * DKH + dseg;                       // + kt*64*2048
    const bf16* vRow = Vg + (size_t)(h * DKH + vd) * Mc + bb * TSEQ + vseg;

    // one K/V tile step: write tile kt from (kI*,vI*), prefetch kt+1 into
    // (kO*,vO*) when pf, then compute tile kt.
    auto tile = [&](int kt, uint4& kI0, uint4& kI1, uint4& vI0, uint4& vI1,
                    uint4& kO0, uint4& kO1, uint4& vO0, uint4& vO1, bool pf) {
        __syncthreads();    // all waves done reading previous tile's LDS
        {
            const int c0 = dseg >> 3, d0 = vseg >> 3;
            *(uint4*)&Kt[skey][((c0 + 0) ^ sk7) << 3] = kI0;
            *(uint4*)&Kt[skey][((c0 + 1) ^ sk7) << 3] = kI1;
            *(uint4*)&Vt[vd][((d0 + 0) ^ (vd & 7)) << 3] = vI0;
            *(uint4*)&Vt[vd][((d0 + 1) ^ (vd & 7)) << 3] = vI1;
        }
        if (pf) {
            const bf16* kp = kRow + (size_t)(kt + 1) * 64 * 2048;
            const bf16* vp = vRow + (kt + 1) * 64;
            kO0 = ((const uint4*)kp)[0];
            kO1 = ((const uint4*)kp)[1];
            vO0 = ((const uint4*)vp)[0];
            vO1 = ((const uint4*)vp)[1];
        }
        __syncthreads();    // tile kt staged

        f32x4 s[4];
        #pragma unroll
        for (int ni = 0; ni < 4; ++ni) s[ni] = (f32x4){0.f, 0.f, 0.f, 0.f};
        #pragma unroll
        for (int ni = 0; ni < 4; ++ni) {
            const int key = ni * 16 + l15;
            #pragma unroll
            for (int kc = 0; kc < 4; ++kc) {
                const int d3 = kc * 4 + quad;
                bf16x8 kb = *(const bf16x8*)&Kt[key][(d3 ^ (key & 7)) << 3];
                s[ni] = MFMA16(qf[kc], kb, s[ni]);
            }
        }

        float tm[4], ts[4];
        #pragma unroll
        for (int rr = 0; rr < 4; ++rr) {
            float v = fmaxf(fmaxf(s[0][rr], s[1][rr]), fmaxf(s[2][rr], s[3][rr]));
            v = fmaxf(v, __shfl_xor(v, 1));
            v = fmaxf(v, __shfl_xor(v, 2));
            v = fmaxf(v, __shfl_xor(v, 4));
            v = fmaxf(v, __shfl_xor(v, 8));
            tm[rr] = v;
        }
        // T13: only rescale when the running max grows by > 8 (wave-uniform)
        int grow = 0;
        #pragma unroll
        for (int rr = 0; rr < 4; ++rr)
            grow |= (tm[rr] > m_i[rr] + 8.f) ? 1 : 0;
        if (__any(grow)) {
            float al[4];
            #pragma unroll
            for (int rr = 0; rr < 4; ++rr) {
                float mn = fmaxf(m_i[rr], tm[rr]);
                al[rr] = __expf(m_i[rr] - mn);
                m_i[rr] = mn;
                l_i[rr] *= al[rr];
            }
            #pragma unroll
            for (int i = 0; i < 8; ++i)
                #pragma unroll
                for (int rr = 0; rr < 4; ++rr) o[i][rr] *= al[rr];
        }
        #pragma unroll
        for (int rr = 0; rr < 4; ++rr) ts[rr] = 0.f;
        #pragma unroll
        for (int ni = 0; ni < 4; ++ni)
            #pragma unroll
            for (int rr = 0; rr < 4; ++rr) {
                float p = __expf(s[ni][rr] - m_i[rr]);
                s[ni][rr] = p;
                ts[rr] += p;
            }
        #pragma unroll
        for (int rr = 0; rr < 4; ++rr) {
            float v = ts[rr];
            v += __shfl_xor(v, 1);
            v += __shfl_xor(v, 2);
            v += __shfl_xor(v, 4);
            v += __shfl_xor(v, 8);
            l_i[rr] += v;
        }

        #pragma unroll
        for (int ni = 0; ni < 4; ++ni)
            #pragma unroll
            for (int rr = 0; rr < 4; ++rr)
                Ps[wave][quad * 4 + rr][ni * 16 + l15] = __float2bfloat16(s[ni][rr]);
        __asm__ __volatile__("s_waitcnt lgkmcnt(0)" ::: "memory");
        bf16x8 pa[2];
        #pragma unroll
        for (int kc2 = 0; kc2 < 2; ++kc2)
            pa[kc2] = *(const bf16x8*)&Ps[wave][l15][kc2 * 32 + quad * 8];

        #pragma unroll
        for (int ni2 = 0; ni2 < 8; ++ni2) {
            const int d = ni2 * 16 + l15;
            #pragma unroll
            for (int kc2 = 0; kc2 < 2; ++kc2) {
                const int key3 = kc2 * 4 + quad;
                bf16x8 vb = *(const bf16x8*)&Vt[d][(key3 ^ (d & 7)) << 3];
                o[ni2] = MFMA16(pa[kc2], vb, o[ni2]);
            }
        }
    };

    // prologue: prefetch tile 0
    uint4 kA0, kA1, vA0, vA1, kB0, kB1, vB0, vB1;
    kA0 = ((const uint4*)kRow)[0];
    kA1 = ((const uint4*)kRow)[1];
    vA0 = ((const uint4*)vRow)[0];
    vA1 = ((const uint4*)vRow)[1];

    #pragma unroll 1
    for (int kt = 0; kt < TSEQ / 64; kt += 2) {
        tile(kt,     kA0, kA1, vA0, vA1, kB0, kB1, vB0, vB1, true);
        tile(kt + 1, kB0, kB1, vB0, vB1, kA0, kA1, vA0, vA1, kt + 2 < TSEQ / 64);
    }

    float rinv[4];
    #pragma unroll
    for (int rr = 0; rr < 4; ++rr) rinv[rr] = 1.0f / l_i[rr];
    const size_t obase = (size_t)bb * TSEQ * DMODEL + (size_t)h * DKH;
    #pragma unroll
    for (int ni2 = 0; ni2 < 8; ++ni2)
        #pragma unroll
        for (int rr = 0; rr < 4; ++rr) {
            int qr = qt * 128 + wave * 16 + quad * 4 + rr;
            Om[obase + (size_t)qr * DMODEL + ni2 * 16 + l15] =
                __float2bfloat16(o[ni2][rr] * rinv[rr]);
        }
}

// ---------------------------------------------------------------------------
extern "C" void kernel_launch(void* const* d_in, const int* in_sizes, int n_in,
                              void* d_out, int out_size, void* d_ws, size_t ws_size,
                              hipStream_t stream) {
    const void* x     = d_in[0];
    const void* W1    = d_in[1];
    const void* b1    = d_in[2];
    const void* W2    = d_in[3];
    const void* b2    = d_in[4];
    const void* ln1_g = d_in[5];
    const void* ln1_b = d_in[6];
    const void* ln2_g = d_in[7];
    const void* ln2_b = d_in[8];
    const void* Wq    = d_in[9];
    const void* bq    = d_in[10];
    const void* Wk    = d_in[11];
    const void* bk    = d_in[12];
    const void* Wv    = d_in[13];
    const void* bv    = d_in[14];
    const void* Wo    = d_in[15];
    const void* bo    = d_in[16];
    const void* Fw1   = d_in[17];
    const void* Fb1   = d_in[18];
    const void* Fw2   = d_in[19];
    const void* Fb2   = d_in[20];

    detect_kernel<<<1, 64, 0, stream>>>(W1);

    // workspace: [Hh | QKb | Vtb | Xc | weight arena], all bf16
    int c = 8;
    while (c > 1 &&
           (5ull * (size_t)c * (1ull << 20) + ARENA_ELEMS) * 2ull > ws_size)
        c >>= 1;
    const int nch = 8 / c;
    const int Mc = c * TSEQ;
    const size_t SL = (size_t)Mc * DMODEL;

    bf16* Hh  = (bf16*)d_ws;      // Mc x 1024
    bf16* QKb = Hh + SL;          // Mc x 2048 (fused Q|K)
    bf16* Vtb = QKb + 2 * SL;     // 1024 x Mc (V^T)
    bf16* Xc  = Vtb + SL;         // Mc x 1024 (fp32-input path only)
    bf16* Wt  = Xc + SL;          // weight arena (fp32-input path only)
    bf16* Hid = QKb;              // Mc x 2048 scratch (downsample hidden)
    bf16* Ffh = QKb;              // Mc x 256 scratch (FFN hidden)
    bf16* Ob  = Hh;               // attn output reuses LN buffer
    void* X = d_out;              // residual stream (flag dtype)

    const bf16* xb  = (const bf16*)x;
    bf16* cW1  = Wt + O_W1;
    bf16* cW2  = Wt + O_W2;
    bf16* cWqk = Wt + O_QK;
    bf16* cWv  = Wt + O_WV;
    bf16* cWo  = Wt + O_WO;
    bf16* cF1  = Wt + O_F1;
    bf16* cF2  = Wt + O_F2;

    cvt_weights<<<832, 256, 0, stream>>>(W1, W2, Wq, Wk, Wv, Wo, Fw1, Fw2, Wt);

    for (int ci = 0; ci < nch; ++ci) {
        const size_t roff = (size_t)ci * Mc * DMODEL;

        cvt_x<<<(int)(SL / 16384), 256, 0, stream>>>(x, roff, Xc);

        gemm256<true, false, 0, false, false><<<dim3(DFF / 128, Mc / 256), 512, 0, stream>>>(
            xb + roff, Xc, (const bf16*)W1, (const bf16*)W1, cW1, cW1,
            b1, nullptr, 0, Hid, 0, Mc, DFF, DMODEL);
        gemm256<false, false, 1, false, false><<<dim3(DMODEL / 128, Mc / 256), 512, 0, stream>>>(
            Hid, Hid, (const bf16*)W2, (const bf16*)W2, cW2, cW2,
            b2, nullptr, 0, X, roff, Mc, DMODEL, DFF);

        for (int l = 0; l < 2; ++l) {
            const size_t wOff   = (size_t)l * DMODEL * DMODEL;       // 1M
            const size_t fOff   = (size_t)l * FHID * DMODEL;         // 256K
            const size_t vOff   = (size_t)l * DMODEL;
            const size_t f1bOff = (size_t)l * FHID;

            const bf16* wqL = (const bf16*)Wq + wOff;
            const bf16* wkL = (const bf16*)Wk + wOff;
            const bf16* wvL = (const bf16*)Wv + wOff;
            const bf16* woL = (const bf16*)Wo + wOff;
            const bf16* f1L = (const bf16*)Fw1 + fOff;
            const bf16* f2L = (const bf16*)Fw2 + fOff;
            const bf16* qkLo = cWqk + (size_t)l * 2097152;
            const bf16* qkHi = qkLo + 1048576;

            ln_wave<<<Mc / 4, 256, 0, stream>>>(X, roff, ln1_g, ln1_b, vOff, Hh);
            // fused Q|K GEMM: N=2048, weight/bias select at col 1024 (uniform)
            gemm256<false, false, 0, false, true><<<dim3(2048 / 128, Mc / 256), 512, 0, stream>>>(
                Hh, Hh, wqL, wkL, qkLo, qkHi,
                bq, bk, vOff, QKb, 0, Mc, 2048, DMODEL);
            // V GEMM with transposed store -> Vtb = V^T [1024][Mc]
            gemm256<false, false, 0, true, false><<<dim3(DMODEL / 128, Mc / 256), 512, 0, stream>>>(
                Hh, Hh, wvL, wvL, cWv + wOff, cWv + wOff,
                bv, nullptr, vOff, Vtb, 0, Mc, DMODEL, DMODEL);

            attn_mfma<<<dim3(TSEQ / 128, NHEAD, c), 512, 0, stream>>>(QKb, Vtb, Ob);

            gemm256<false, true, 1, false, false><<<dim3(DMODEL / 128, Mc / 256), 512, 0, stream>>>(
                Ob, Ob, woL, woL, cWo + wOff, cWo + wOff,
                bo, nullptr, vOff, X, roff, Mc, DMODEL, DMODEL);

            ln_wave<<<Mc / 4, 256, 0, stream>>>(X, roff, ln2_g, ln2_b, vOff, Hh);
            gemm_bf16<true, false, 0, false, false><<<dim3(FHID / 128, Mc / 128), 256, 0, stream>>>(
                Hh, Hh, f1L, f1L, cF1 + fOff, cF1 + fOff,
                Fb1, nullptr, f1bOff, Ffh, 0, Mc, FHID, DMODEL);
            gemm_bf16<false, true, 1, false, false><<<dim3(DMODEL / 128, Mc / 128), 256, 0, stream>>>(
                Ffh, Ffh, f2L, f2L, cF2 + fOff, cF2 + fOff,
                Fb2, nullptr, vOff, X, roff, Mc, DMODEL, FHID);
        }
    }
}

// Round 8
// 844.142 us; speedup vs baseline: 1.0271x; 1.0271x over previous
//
#include <hip/hip_runtime.h>
#include <hip/hip_bf16.h>

// ---------------------------------------------------------------------------
// CorrectTransformerAdaptor — Round 12: revert attn T14 (regressed: VGPR
//   60->76, occ 36->21%, 80.8->90.7us); attn back to round-6 version.
//   gemm256 keeps 256x128/BK=32 dbuf shape but uses T4 counted vmcnt:
//   raw s_barrier + s_waitcnt vmcnt(3) (not the __syncthreads vmcnt(0)
//   drain) so the 3 prefetch loads stay in flight across the barrier.
//   Classic dbuf 2-barrier discipline; sched_barrier(0) after waits
//   (rule #18); swizzle pair unchanged (rule #21).
// ---------------------------------------------------------------------------

#define DMODEL 1024
#define DFF 2048
#define FHID 256
#define NHEAD 8
#define DKH 128
#define TSEQ 1024

typedef __hip_bfloat16 bf16;
typedef __attribute__((ext_vector_type(8))) short bf16x8;   // 8 bf16 = 4 VGPR
typedef __attribute__((ext_vector_type(4))) float f32x4;

#define MFMA16(a, b, c) __builtin_amdgcn_mfma_f32_16x16x32_bf16(a, b, c, 0, 0, 0)

__device__ int g_is_bf16;

// one coherent load per block, broadcast via LDS (needs all threads at entry)
__device__ __forceinline__ bool flagbf_block() {
    __shared__ int fsh;
    if (threadIdx.x == 0)
        fsh = __hip_atomic_load(&g_is_bf16, __ATOMIC_ACQUIRE,
                                __HIP_MEMORY_SCOPE_AGENT);
    __syncthreads();
    return fsh != 0;
}
__device__ __forceinline__ float gload(const void* p, size_t i, bool bf) {
    return bf ? __bfloat162float(((const bf16*)p)[i]) : ((const float*)p)[i];
}
__device__ __forceinline__ void gstore(void* p, size_t i, bool bf, float v) {
    if (bf) ((bf16*)p)[i] = __float2bfloat16(v);
    else    ((float*)p)[i] = v;
}

// direct global->LDS, 16 bytes/lane. LDS base must be wave-uniform (m104);
// lane writes at base + lane*16. Global address is per-lane.
__device__ __forceinline__ void async16(const bf16* g, const bf16* l) {
    __builtin_amdgcn_global_load_lds(
        (const __attribute__((address_space(1))) void*)g,
        (__attribute__((address_space(3))) void*)l, 16, 0, 0);
}

// ---- dtype probe (64 lanes, ballot) ---------------------------------------
__global__ void detect_kernel(const void* __restrict__ probe) {
    const int lane = threadIdx.x & 63;
    const bf16* h = (const bf16*)probe;
    int ok = 1;
    #pragma unroll
    for (int j = 0; j < 4; ++j) {
        float v = __bfloat162float(h[lane * 4 + j]);
        if (!(fabsf(v) <= 1000.0f)) ok = 0;   // catches huge AND NaN
    }
    unsigned long long m = __ballot(ok);
    if (lane == 0)
        __hip_atomic_store(&g_is_bf16, m == ~0ull ? 1 : 0, __ATOMIC_RELEASE,
                           __HIP_MEMORY_SCOPE_AGENT);
}

// ---- weight arena offsets (bf16 elems) — fp32-input path only -------------
#define O_W1  0ull
#define O_W2  2097152ull
#define O_QK  4194304ull
#define O_WV  8388608ull
#define O_WO  10485760ull
#define O_F1  12582912ull
#define O_F2  13107200ull
#define ARENA_ELEMS 13631488ull

// one block = 16384 elems; per iteration a wave does unit-stride float4
// reads (1KB/instr) and unit-stride uint2 bf16 writes (512B/instr).
__global__ __launch_bounds__(256) void cvt_weights(
        const void* W1, const void* W2, const void* Wq, const void* Wk,
        const void* Wv, const void* Wo, const void* F1, const void* F2,
        bf16* __restrict__ arena) {
    if (flagbf_block()) return;   // bf16 inputs: GEMMs read them directly
    int b = blockIdx.x;
    const float* src; bf16* dst;
    if      (b < 128)  {           src = (const float*)W1 + (size_t)b * 16384;
                         dst = arena + O_W1 + (size_t)b * 16384; }
    else if (b < 256)  { b -= 128; src = (const float*)W2 + (size_t)b * 16384;
                         dst = arena + O_W2 + (size_t)b * 16384; }
    else if (b < 384)  { b -= 256; src = (const float*)Wq + (size_t)b * 16384;
                         dst = arena + O_QK + (size_t)(b >> 6) * 2097152
                                            + (size_t)(b & 63) * 16384; }
    else if (b < 512)  { b -= 384; src = (const float*)Wk + (size_t)b * 16384;
                         dst = arena + O_QK + (size_t)(b >> 6) * 2097152
                                            + 1048576 + (size_t)(b & 63) * 16384; }
    else if (b < 640)  { b -= 512; src = (const float*)Wv + (size_t)b * 16384;
                         dst = arena + O_WV + (size_t)b * 16384; }
    else if (b < 768)  { b -= 640; src = (const float*)Wo + (size_t)b * 16384;
                         dst = arena + O_WO + (size_t)b * 16384; }
    else if (b < 800)  { b -= 768; src = (const float*)F1 + (size_t)b * 16384;
                         dst = arena + O_F1 + (size_t)b * 16384; }
    else               { b -= 800; src = (const float*)F2 + (size_t)b * 16384;
                         dst = arena + O_F2 + (size_t)b * 16384; }
    const int tid = threadIdx.x;
    #pragma unroll
    for (int it = 0; it < 16; ++it) {
        const int e = it * 1024 + tid * 4;
        float4 f = *(const float4*)(src + e);
        bf16 t[4] = {__float2bfloat16(f.x), __float2bfloat16(f.y),
                     __float2bfloat16(f.z), __float2bfloat16(f.w)};
        *(uint2*)(dst + e) = *(const uint2*)t;
    }
}

__global__ __launch_bounds__(256) void cvt_x(
        const void* __restrict__ X, size_t x_off, bf16* __restrict__ dst) {
    if (flagbf_block()) return;   // bf16 x is consumed in place
    const float* src = (const float*)X + x_off + (size_t)blockIdx.x * 16384;
    bf16* d = dst + (size_t)blockIdx.x * 16384;
    const int tid = threadIdx.x;
    #pragma unroll
    for (int it = 0; it < 16; ++it) {
        const int e = it * 1024 + tid * 4;
        float4 f = *(const float4*)(src + e);
        bf16 t[4] = {__float2bfloat16(f.x), __float2bfloat16(f.y),
                     __float2bfloat16(f.z), __float2bfloat16(f.w)};
        *(uint2*)(d + e) = *(const uint2*)t;
    }
}

// ---------------- 256x128 2-phase GEMM, T4 counted vmcnt -------------------
// 512 thr = 8 waves (4M x 2N), per-wave 64x64 out, BK=32, dbuf LDS 48KB.
// Issue t+1's 3 loads -> vmcnt(3) (t landed) -> barrier -> compute(buf) ->
// barrier (reads done before t+2 overwrites). No vmcnt(0) drain in loop.
template <bool RELU, bool ADD, int CMODE, bool TRANSC, bool BIAS2>
__global__ __launch_bounds__(512, 4) void gemm256(
        const bf16* Abf, const bf16* Acv,
        const bf16* Wlo_bf, const bf16* Whi_bf,
        const bf16* Wlo_cv, const bf16* Whi_cv,
        const void* __restrict__ bias, const void* __restrict__ bias2,
        size_t b_off,
        void* __restrict__ C, size_t c_off,
        int M, int N, int K) {
    const bool fl = flagbf_block();
    const bf16* A   = fl ? Abf : Acv;
    const bf16* Wlo = fl ? Wlo_bf : Wlo_cv;
    const bf16* Whi = fl ? Whi_bf : Whi_cv;

    __shared__ __align__(16) bf16 As[2][256 * 32];   // 32 KB
    __shared__ __align__(16) bf16 Bs[2][128 * 32];   // 16 KB

    // XCD band remap over (gx = N/128, gy = M/256)
    const int gx = gridDim.x;
    const int lin = blockIdx.x + gx * blockIdx.y;
    int bm, bn;
    if ((gridDim.y & 7) == 0) {
        const int xcd = lin & 7, j = lin >> 3;
        const int rpx = gridDim.y >> 3;
        bm = (xcd * rpx + (j / gx)) * 256;
        bn = (j % gx) * 128;
    } else {
        bm = blockIdx.y * 256;
        bn = blockIdx.x * 128;
    }

    const int tid = threadIdx.x;
    const int wave = tid >> 6, lane = tid & 63;
    const int quad = lane >> 4, l15 = lane & 15;
    const int wm = wave >> 1, wn = wave & 1;

    const bf16* Wp;
    int bnr;
    if (BIAS2 && bn >= 1024) { Wp = Whi; bnr = bn - 1024; }
    else                     { Wp = Wlo; bnr = bn; }

    // staging: lane covers row lane>>2 (of 16), chunk lane&3; source chunk
    // pre-swizzled by ((row>>1)&3) == ((lane>>3)&3) for 16-aligned bases.
    const int srow = lane >> 2;
    const int schunk = (lane & 3) ^ ((lane >> 3) & 3);
    const bf16* gaBase = A  + (size_t)(bm  + wave * 32 + srow) * K + schunk * 8;
    const bf16* gbBase = Wp + (size_t)(bnr + wave * 16 + srow) * K + schunk * 8;
    const int laOff0 = (wave * 32) * 32;
    const int laOff1 = (wave * 32 + 16) * 32;
    const int lbOff  = (wave * 16) * 32;

    f32x4 acc[4][4];
    #pragma unroll
    for (int i = 0; i < 4; ++i)
        #pragma unroll
        for (int j = 0; j < 4; ++j) acc[i][j] = (f32x4){0.f, 0.f, 0.f, 0.f};

    const int nt = K >> 5;
    int cur = 0;

    // prologue: stage K-tile 0 into buf 0 (3 loads in flight)
    async16(gaBase, &As[0][laOff0]);
    async16(gaBase + (size_t)16 * K, &As[0][laOff1]);
    async16(gbBase, &Bs[0][lbOff]);

    for (int t = 0; t < nt; ++t) {
        if (t + 1 < nt) {                       // prefetch next tile
            const int kn = (t + 1) << 5;
            async16(gaBase + kn, &As[cur ^ 1][laOff0]);
            async16(gaBase + (size_t)16 * K + kn, &As[cur ^ 1][laOff1]);
            async16(gbBase + kn, &Bs[cur ^ 1][lbOff]);
            __asm__ __volatile__("s_waitcnt vmcnt(3)" ::: "memory");
        } else {
            __asm__ __volatile__("s_waitcnt vmcnt(0)" ::: "memory");
        }
        __builtin_amdgcn_s_barrier();           // buf[cur] visible to all
        __builtin_amdgcn_sched_barrier(0);

        bf16x8 bfr[4];
        #pragma unroll
        for (int ni = 0; ni < 4; ++ni) {
            const int row = wn * 64 + ni * 16 + l15;
            bfr[ni] = *(const bf16x8*)
                &Bs[cur][row * 32 + ((quad ^ ((row >> 1) & 3)) << 3)];
        }
        #pragma unroll
        for (int mi = 0; mi < 4; ++mi) {
            const int row = wm * 64 + mi * 16 + l15;
            bf16x8 af = *(const bf16x8*)
                &As[cur][row * 32 + ((quad ^ ((row >> 1) & 3)) << 3)];
            #pragma unroll
            for (int ni = 0; ni < 4; ++ni)
                acc[mi][ni] = MFMA16(af, bfr[ni], acc[mi][ni]);
        }
        __builtin_amdgcn_sched_barrier(0);
        __builtin_amdgcn_s_barrier();           // reads of buf[cur] done
        cur ^= 1;
    }

    // epilogue: acc row = quad*4+rr, col = lane&15 (verified m89/m91 layout)
    const bool cbf = CMODE ? fl : true;
    #pragma unroll
    for (int ni = 0; ni < 4; ++ni) {
        const int col = bn + wn * 64 + ni * 16 + l15;
        float bv;
        if (BIAS2) bv = col < 1024 ? gload(bias, b_off + col, fl)
                                   : gload(bias2, b_off + col - 1024, fl);
        else       bv = gload(bias, b_off + col, fl);
        #pragma unroll
        for (int mi = 0; mi < 4; ++mi) {
            const int row0 = bm + wm * 64 + mi * 16 + quad * 4;
            if (TRANSC) {
                bf16 pk[4];
                #pragma unroll
                for (int rr = 0; rr < 4; ++rr)
                    pk[rr] = __float2bfloat16(acc[mi][ni][rr] + bv);
                *(uint2*)((bf16*)C + c_off + (size_t)col * M + row0) =
                    *(const uint2*)pk;
            } else {
                #pragma unroll
                for (int rr = 0; rr < 4; ++rr) {
                    float v = acc[mi][ni][rr] + bv;
                    if (RELU) v = fmaxf(v, 0.f);
                    size_t idx = c_off + (size_t)(row0 + rr) * N + col;
                    if (ADD) v += gload(C, idx, cbf);
                    gstore(C, idx, cbf, v);
                }
            }
        }
    }
}

// ---------------- 128x128 m97 GEMM (kept for F1/F2) ------------------------
template <bool RELU, bool ADD, int CMODE, bool TRANSC, bool BIAS2>
__global__ __launch_bounds__(256) void gemm_bf16(
        const bf16* Abf, const bf16* Acv,
        const bf16* Wlo_bf, const bf16* Whi_bf,
        const bf16* Wlo_cv, const bf16* Whi_cv,
        const void* __restrict__ bias, const void* __restrict__ bias2,
        size_t b_off,
        void* __restrict__ C, size_t c_off,
        int M, int N, int K) {
    const bool fl = flagbf_block();
    const bf16* A   = fl ? Abf : Acv;
    const bf16* Wlo = fl ? Wlo_bf : Wlo_cv;
    const bf16* Whi = fl ? Whi_bf : Whi_cv;

    __shared__ __align__(16) bf16 As[128 * 64];
    __shared__ __align__(16) bf16 Bs[128 * 64];

    const int gx = gridDim.x;
    const int lin = blockIdx.x + gx * blockIdx.y;
    int bm, bn;
    if ((gridDim.y & 7) == 0) {
        const int xcd = lin & 7, j = lin >> 3;
        const int rpx = gridDim.y >> 3;
        bm = (xcd * rpx + j / gx) * 128;
        bn = (j % gx) * 128;
    } else {
        bm = blockIdx.y * 128;
        bn = blockIdx.x * 128;
    }

    const int tid = threadIdx.x;
    const int wave = tid >> 6, lane = tid & 63;
    const int quad = lane >> 4, l15 = lane & 15;
    const int wr = wave >> 1, wc = wave & 1;
    const int l8 = lane >> 3, l7 = lane & 7;
    const int swz = l7 ^ l8;          // row&7 == l8 for our staging rows

    const bf16* Wp;
    int bnr;
    if (BIAS2 && bn >= 1024) { Wp = Whi; bnr = bn - 1024; }
    else                     { Wp = Wlo; bnr = bn; }

    f32x4 acc[4][4];
    #pragma unroll
    for (int i = 0; i < 4; ++i)
        #pragma unroll
        for (int j2 = 0; j2 < 4; ++j2) acc[i][j2] = (f32x4){0.f, 0.f, 0.f, 0.f};

    const bf16* ga0 = A  + (size_t)(bm  + wave * 32 + l8) * K + swz * 8;
    const bf16* gb0 = Wp + (size_t)(bnr + wave * 32 + l8) * K + swz * 8;
    bf16* la0 = &As[(wave * 32) * 64];
    bf16* lb0 = &Bs[(wave * 32) * 64];

    for (int k0 = 0; k0 < K; k0 += 64) {
        __syncthreads();
        #pragma unroll
        for (int i = 0; i < 4; ++i) {
            async16(ga0 + (size_t)(i * 8) * K + k0, la0 + i * 512);
            async16(gb0 + (size_t)(i * 8) * K + k0, lb0 + i * 512);
        }
        __syncthreads();

        #pragma unroll
        for (int ks = 0; ks < 2; ++ks) {
            bf16x8 af[4], bfr[4];
            #pragma unroll
            for (int mi = 0; mi < 4; ++mi) {
                const int row = wr * 64 + mi * 16 + l15;
                af[mi] = *(const bf16x8*)
                    &As[row * 64 + ((((ks << 2) | quad) ^ (row & 7)) << 3)];
            }
            #pragma unroll
            for (int ni = 0; ni < 4; ++ni) {
                const int row = wc * 64 + ni * 16 + l15;
                bfr[ni] = *(const bf16x8*)
                    &Bs[row * 64 + ((((ks << 2) | quad) ^ (row & 7)) << 3)];
            }
            #pragma unroll
            for (int mi = 0; mi < 4; ++mi)
                #pragma unroll
                for (int ni = 0; ni < 4; ++ni)
                    acc[mi][ni] = MFMA16(af[mi], bfr[ni], acc[mi][ni]);
        }
    }

    const bool cbf = CMODE ? fl : true;
    #pragma unroll
    for (int ni = 0; ni < 4; ++ni) {
        const int col = bn + wc * 64 + ni * 16 + l15;
        float bv;
        if (BIAS2) bv = col < 1024 ? gload(bias, b_off + col, fl)
                                   : gload(bias2, b_off + col - 1024, fl);
        else       bv = gload(bias, b_off + col, fl);
        #pragma unroll
        for (int mi = 0; mi < 4; ++mi) {
            const int row0 = bm + wr * 64 + mi * 16 + quad * 4;
            if (TRANSC) {
                bf16 pk[4];
                #pragma unroll
                for (int rr = 0; rr < 4; ++rr)
                    pk[rr] = __float2bfloat16(acc[mi][ni][rr] + bv);
                *(uint2*)((bf16*)C + c_off + (size_t)col * M + row0) =
                    *(const uint2*)pk;
            } else {
                #pragma unroll
                for (int rr = 0; rr < 4; ++rr) {
                    float v = acc[mi][ni][rr] + bv;
                    if (RELU) v = fmaxf(v, 0.f);
                    size_t idx = c_off + (size_t)(row0 + rr) * N + col;
                    if (ADD) v += gload(C, idx, cbf);
                    gstore(C, idx, cbf, v);
                }
            }
        }
    }
}

// ---------------- LayerNorm: one wave per row, shuffle-only ----------------
__global__ __launch_bounds__(256) void ln_wave(
        const void* __restrict__ X, size_t x_off,
        const void* __restrict__ g, const void* __restrict__ b, size_t gb_off,
        bf16* __restrict__ H) {
    const bool fl = flagbf_block();
    const int lane = threadIdx.x & 63;
    const int row = blockIdx.x * 4 + (threadIdx.x >> 6);
    const size_t xrow = x_off + (size_t)row * DMODEL;

    float v[16];
    if (fl) {
        const bf16* xp = (const bf16*)X + xrow;
        #pragma unroll
        for (int c = 0; c < 2; ++c) {
            uint4 raw = *(const uint4*)(xp + c * 512 + lane * 8);
            const bf16* rb = (const bf16*)&raw;
            #pragma unroll
            for (int j = 0; j < 8; ++j) v[c * 8 + j] = __bfloat162float(rb[j]);
        }
    } else {
        const float* xp = (const float*)X + xrow;
        #pragma unroll
        for (int c = 0; c < 4; ++c) {
            float4 f = *(const float4*)(xp + c * 256 + lane * 4);
            v[c * 4 + 0] = f.x; v[c * 4 + 1] = f.y;
            v[c * 4 + 2] = f.z; v[c * 4 + 3] = f.w;
        }
    }

    float s = 0.f;
    #pragma unroll
    for (int j = 0; j < 16; ++j) s += v[j];
    #pragma unroll
    for (int off = 32; off > 0; off >>= 1) s += __shfl_xor(s, off);
    const float mean = s * (1.f / DMODEL);

    float vs = 0.f;
    #pragma unroll
    for (int j = 0; j < 16; ++j) { float d = v[j] - mean; vs += d * d; }
    #pragma unroll
    for (int off = 32; off > 0; off >>= 1) vs += __shfl_xor(vs, off);
    const float rstd = rsqrtf(vs * (1.f / DMODEL) + 1e-12f);

    bf16* h = H + (size_t)row * DMODEL;
    if (fl) {
        const bf16* gp = (const bf16*)g + gb_off;
        const bf16* bp = (const bf16*)b + gb_off;
        #pragma unroll
        for (int c = 0; c < 2; ++c) {
            const int o = c * 512 + lane * 8;
            uint4 gr = *(const uint4*)(gp + o);
            uint4 br = *(const uint4*)(bp + o);
            const bf16* gg = (const bf16*)&gr;
            const bf16* bb = (const bf16*)&br;
            bf16 outv[8];
            #pragma unroll
            for (int j = 0; j < 8; ++j)
                outv[j] = __float2bfloat16((v[c * 8 + j] - mean) * rstd *
                          __bfloat162float(gg[j]) + __bfloat162float(bb[j]));
            *(uint4*)(h + o) = *(const uint4*)outv;
        }
    } else {
        const float* gp = (const float*)g + gb_off;
        const float* bp = (const float*)b + gb_off;
        #pragma unroll
        for (int c = 0; c < 4; ++c) {
            const int o = c * 256 + lane * 4;
            float4 gr = *(const float4*)(gp + o);
            float4 br = *(const float4*)(bp + o);
            const float gg[4] = {gr.x, gr.y, gr.z, gr.w};
            const float bb[4] = {br.x, br.y, br.z, br.w};
            bf16 outv[4];
            #pragma unroll
            for (int j = 0; j < 4; ++j)
                outv[j] = __float2bfloat16((v[c * 4 + j] - mean) * rstd * gg[j] + bb[j]);
            *(uint2*)(h + o) = *(const uint2*)outv;
        }
    }
}

// ---------------- Flash-style MFMA attention (round-6 version) -------------
// Grid: (TSEQ/128, NHEAD, c). Block: 512 threads = 8 waves, wave w owns
// q-rows [qt*128 + w*16, +16). K loop over 64-key tiles staged in LDS.
// XCD swizzle: each XCD owns whole (bb, all-head) groups. T13 defer-rescale.
__global__ __launch_bounds__(512) void attn_mfma(
        const bf16* __restrict__ QK, const bf16* __restrict__ Vg,
        bf16* __restrict__ Om) {
    const int cch = (int)gridDim.z;                  // chunk count c
    const int lin = blockIdx.x + (int)gridDim.x *
                    (blockIdx.y + (int)gridDim.y * blockIdx.z);
    const int xcd = lin & 7, j = lin >> 3;           // 64c blocks, div by 8
    const int qt = j & 7, gl = j >> 3;               // gl in [0,c)
    const int g = xcd * cch + gl;                    // (h,bb) group id
    const int h = g & 7, bb = g >> 3;

    const int Mc = cch * TSEQ;
    const int tid = threadIdx.x;
    const int wave = tid >> 6, lane = tid & 63;
    const int quad = lane >> 4, l15 = lane & 15;

    __shared__ __align__(16) bf16 Kt[64][128];
    __shared__ __align__(16) bf16 Vt[128][64];
    __shared__ __align__(16) bf16 Ps[8][16][72];

    const int qrow = qt * 128 + wave * 16 + l15;
    const float scale = 0.08838834764831845f;  // 1/sqrt(128)

    bf16x8 qf[4];
    #pragma unroll
    for (int kc = 0; kc < 4; ++kc) {
        uint4 raw = *(const uint4*)(QK + (size_t)(bb * TSEQ + qrow) * 2048 +
                                    h * DKH + kc * 32 + quad * 8);
        const bf16* rb = (const bf16*)&raw;
        bf16 tmp[8];
        #pragma unroll
        for (int j2 = 0; j2 < 8; ++j2)
            tmp[j2] = __float2bfloat16(__bfloat162float(rb[j2]) * scale);
        qf[kc] = *(const bf16x8*)tmp;
    }

    f32x4 o[8];
    #pragma unroll
    for (int i = 0; i < 8; ++i) o[i] = (f32x4){0.f, 0.f, 0.f, 0.f};
    float m_i[4] = {-1e30f, -1e30f, -1e30f, -1e30f};
    float l_i[4] = {0.f, 0.f, 0.f, 0.f};

    const int skey = tid >> 3;              // K staging: row = key (0..63)
    const int dseg = (tid & 7) * 16;        // 2 x uint4 per thread
    const int sk7 = skey & 7;
    const int vd = tid >> 2;                // V staging: row = d (0..127)
    const int vseg = (tid & 3) * 16;        // 2 x uint4 per thread

    for (int kt = 0; kt < TSEQ / 64; ++kt) {
        __syncthreads();
        {
            const bf16* kp = QK + (size_t)(bb * TSEQ + kt * 64 + skey) * 2048 +
                             1024 + h * DKH + dseg;
            const bf16* vp = Vg + (size_t)(h * DKH + vd) * Mc + bb * TSEQ +
                             kt * 64 + vseg;
            uint4 kv[2], vv[2];
            #pragma unroll
            for (int g2 = 0; g2 < 2; ++g2) { kv[g2] = ((const uint4*)kp)[g2]; vv[g2] = ((const uint4*)vp)[g2]; }
            #pragma unroll
            for (int g2 = 0; g2 < 2; ++g2) {
                int c = (dseg >> 3) + g2;
                *(uint4*)&Kt[skey][(c ^ sk7) << 3] = kv[g2];
            }
            #pragma unroll
            for (int g2 = 0; g2 < 2; ++g2) {
                int c = (vseg >> 3) + g2;
                *(uint4*)&Vt[vd][(c ^ (vd & 7)) << 3] = vv[g2];
            }
        }
        __syncthreads();

        f32x4 s[4];
        #pragma unroll
        for (int ni = 0; ni < 4; ++ni) s[ni] = (f32x4){0.f, 0.f, 0.f, 0.f};
        #pragma unroll
        for (int ni = 0; ni < 4; ++ni) {
            const int key = ni * 16 + l15;
            #pragma unroll
            for (int kc = 0; kc < 4; ++kc) {
                const int d3 = kc * 4 + quad;
                bf16x8 kb = *(const bf16x8*)&Kt[key][(d3 ^ (key & 7)) << 3];
                s[ni] = MFMA16(qf[kc], kb, s[ni]);
            }
        }

        float tm[4], ts[4];
        #pragma unroll
        for (int rr = 0; rr < 4; ++rr) {
            float v = fmaxf(fmaxf(s[0][rr], s[1][rr]), fmaxf(s[2][rr], s[3][rr]));
            v = fmaxf(v, __shfl_xor(v, 1));
            v = fmaxf(v, __shfl_xor(v, 2));
            v = fmaxf(v, __shfl_xor(v, 4));
            v = fmaxf(v, __shfl_xor(v, 8));
            tm[rr] = v;
        }
        // T13: only rescale when the running max grows by > 8 (wave-uniform)
        int grow = 0;
        #pragma unroll
        for (int rr = 0; rr < 4; ++rr)
            grow |= (tm[rr] > m_i[rr] + 8.f) ? 1 : 0;
        if (__any(grow)) {
            float al[4];
            #pragma unroll
            for (int rr = 0; rr < 4; ++rr) {
                float mn = fmaxf(m_i[rr], tm[rr]);
                al[rr] = __expf(m_i[rr] - mn);
                m_i[rr] = mn;
                l_i[rr] *= al[rr];
            }
            #pragma unroll
            for (int i = 0; i < 8; ++i)
                #pragma unroll
                for (int rr = 0; rr < 4; ++rr) o[i][rr] *= al[rr];
        }
        #pragma unroll
        for (int rr = 0; rr < 4; ++rr) ts[rr] = 0.f;
        #pragma unroll
        for (int ni = 0; ni < 4; ++ni)
            #pragma unroll
            for (int rr = 0; rr < 4; ++rr) {
                float p = __expf(s[ni][rr] - m_i[rr]);
                s[ni][rr] = p;
                ts[rr] += p;
            }
        #pragma unroll
        for (int rr = 0; rr < 4; ++rr) {
            float v = ts[rr];
            v += __shfl_xor(v, 1);
            v += __shfl_xor(v, 2);
            v += __shfl_xor(v, 4);
            v += __shfl_xor(v, 8);
            l_i[rr] += v;
        }

        #pragma unroll
        for (int ni = 0; ni < 4; ++ni)
            #pragma unroll
            for (int rr = 0; rr < 4; ++rr)
                Ps[wave][quad * 4 + rr][ni * 16 + l15] = __float2bfloat16(s[ni][rr]);
        __asm__ __volatile__("s_waitcnt lgkmcnt(0)" ::: "memory");
        bf16x8 pa[2];
        #pragma unroll
        for (int kc2 = 0; kc2 < 2; ++kc2)
            pa[kc2] = *(const bf16x8*)&Ps[wave][l15][kc2 * 32 + quad * 8];

        #pragma unroll
        for (int ni2 = 0; ni2 < 8; ++ni2) {
            const int d = ni2 * 16 + l15;
            #pragma unroll
            for (int kc2 = 0; kc2 < 2; ++kc2) {
                const int key3 = kc2 * 4 + quad;
                bf16x8 vb = *(const bf16x8*)&Vt[d][(key3 ^ (d & 7)) << 3];
                o[ni2] = MFMA16(pa[kc2], vb, o[ni2]);
            }
        }
    }

    float rinv[4];
    #pragma unroll
    for (int rr = 0; rr < 4; ++rr) rinv[rr] = 1.0f / l_i[rr];
    const size_t obase = (size_t)bb * TSEQ * DMODEL + (size_t)h * DKH;
    #pragma unroll
    for (int ni2 = 0; ni2 < 8; ++ni2)
        #pragma unroll
        for (int rr = 0; rr < 4; ++rr) {
            int qr = qt * 128 + wave * 16 + quad * 4 + rr;
            Om[obase + (size_t)qr * DMODEL + ni2 * 16 + l15] =
                __float2bfloat16(o[ni2][rr] * rinv[rr]);
        }
}

// ---------------------------------------------------------------------------
extern "C" void kernel_launch(void* const* d_in, const int* in_sizes, int n_in,
                              void* d_out, int out_size, void* d_ws, size_t ws_size,
                              hipStream_t stream) {
    const void* x     = d_in[0];
    const void* W1    = d_in[1];
    const void* b1    = d_in[2];
    const void* W2    = d_in[3];
    const void* b2    = d_in[4];
    const void* ln1_g = d_in[5];
    const void* ln1_b = d_in[6];
    const void* ln2_g = d_in[7];
    const void* ln2_b = d_in[8];
    const void* Wq    = d_in[9];
    const void* bq    = d_in[10];
    const void* Wk    = d_in[11];
    const void* bk    = d_in[12];
    const void* Wv    = d_in[13];
    const void* bv    = d_in[14];
    const void* Wo    = d_in[15];
    const void* bo    = d_in[16];
    const void* Fw1   = d_in[17];
    const void* Fb1   = d_in[18];
    const void* Fw2   = d_in[19];
    const void* Fb2   = d_in[20];

    detect_kernel<<<1, 64, 0, stream>>>(W1);

    // workspace: [Hh | QKb | Vtb | Xc | weight arena], all bf16
    int c = 8;
    while (c > 1 &&
           (5ull * (size_t)c * (1ull << 20) + ARENA_ELEMS) * 2ull > ws_size)
        c >>= 1;
    const int nch = 8 / c;
    const int Mc = c * TSEQ;
    const size_t SL = (size_t)Mc * DMODEL;

    bf16* Hh  = (bf16*)d_ws;      // Mc x 1024
    bf16* QKb = Hh + SL;          // Mc x 2048 (fused Q|K)
    bf16* Vtb = QKb + 2 * SL;     // 1024 x Mc (V^T)
    bf16* Xc  = Vtb + SL;         // Mc x 1024 (fp32-input path only)
    bf16* Wt  = Xc + SL;          // weight arena (fp32-input path only)
    bf16* Hid = QKb;              // Mc x 2048 scratch (downsample hidden)
    bf16* Ffh = QKb;              // Mc x 256 scratch (FFN hidden)
    bf16* Ob  = Hh;               // attn output reuses LN buffer
    void* X = d_out;              // residual stream (flag dtype)

    const bf16* xb  = (const bf16*)x;
    bf16* cW1  = Wt + O_W1;
    bf16* cW2  = Wt + O_W2;
    bf16* cWqk = Wt + O_QK;
    bf16* cWv  = Wt + O_WV;
    bf16* cWo  = Wt + O_WO;
    bf16* cF1  = Wt + O_F1;
    bf16* cF2  = Wt + O_F2;

    cvt_weights<<<832, 256, 0, stream>>>(W1, W2, Wq, Wk, Wv, Wo, Fw1, Fw2, Wt);

    for (int ci = 0; ci < nch; ++ci) {
        const size_t roff = (size_t)ci * Mc * DMODEL;

        cvt_x<<<(int)(SL / 16384), 256, 0, stream>>>(x, roff, Xc);

        gemm256<true, false, 0, false, false><<<dim3(DFF / 128, Mc / 256), 512, 0, stream>>>(
            xb + roff, Xc, (const bf16*)W1, (const bf16*)W1, cW1, cW1,
            b1, nullptr, 0, Hid, 0, Mc, DFF, DMODEL);
        gemm256<false, false, 1, false, false><<<dim3(DMODEL / 128, Mc / 256), 512, 0, stream>>>(
            Hid, Hid, (const bf16*)W2, (const bf16*)W2, cW2, cW2,
            b2, nullptr, 0, X, roff, Mc, DMODEL, DFF);

        for (int l = 0; l < 2; ++l) {
            const size_t wOff   = (size_t)l * DMODEL * DMODEL;       // 1M
            const size_t fOff   = (size_t)l * FHID * DMODEL;         // 256K
            const size_t vOff   = (size_t)l * DMODEL;
            const size_t f1bOff = (size_t)l * FHID;

            const bf16* wqL = (const bf16*)Wq + wOff;
            const bf16* wkL = (const bf16*)Wk + wOff;
            const bf16* wvL = (const bf16*)Wv + wOff;
            const bf16* woL = (const bf16*)Wo + wOff;
            const bf16* f1L = (const bf16*)Fw1 + fOff;
            const bf16* f2L = (const bf16*)Fw2 + fOff;
            const bf16* qkLo = cWqk + (size_t)l * 2097152;
            const bf16* qkHi = qkLo + 1048576;

            ln_wave<<<Mc / 4, 256, 0, stream>>>(X, roff, ln1_g, ln1_b, vOff, Hh);
            // fused Q|K GEMM: N=2048, weight/bias select at col 1024 (uniform)
            gemm256<false, false, 0, false, true><<<dim3(2048 / 128, Mc / 256), 512, 0, stream>>>(
                Hh, Hh, wqL, wkL, qkLo, qkHi,
                bq, bk, vOff, QKb, 0, Mc, 2048, DMODEL);
            // V GEMM with transposed store -> Vtb = V^T [1024][Mc]
            gemm256<false, false, 0, true, false><<<dim3(DMODEL / 128, Mc / 256), 512, 0, stream>>>(
                Hh, Hh, wvL, wvL, cWv + wOff, cWv + wOff,
                bv, nullptr, vOff, Vtb, 0, Mc, DMODEL, DMODEL);

            attn_mfma<<<dim3(TSEQ / 128, NHEAD, c), 512, 0, stream>>>(QKb, Vtb, Ob);

            gemm256<false, true, 1, false, false><<<dim3(DMODEL / 128, Mc / 256), 512, 0, stream>>>(
                Ob, Ob, woL, woL, cWo + wOff, cWo + wOff,
                bo, nullptr, vOff, X, roff, Mc, DMODEL, DMODEL);

            ln_wave<<<Mc / 4, 256, 0, stream>>>(X, roff, ln2_g, ln2_b, vOff, Hh);
            gemm_bf16<true, false, 0, false, false><<<dim3(FHID / 128, Mc / 128), 256, 0, stream>>>(
                Hh, Hh, f1L, f1L, cF1 + fOff, cF1 + fOff,
                Fb1, nullptr, f1bOff, Ffh, 0, Mc, FHID, DMODEL);
            gemm_bf16<false, true, 1, false, false><<<dim3(DMODEL / 128, Mc / 128), 256, 0, stream>>>(
                Ffh, Ffh, f2L, f2L, cF2 + fOff, cF2 + fOff,
                Fb2, nullptr, vOff, X, roff, Mc, DMODEL, FHID);
        }
    }
}

// Round 9
// 843.832 us; speedup vs baseline: 1.0275x; 1.0004x over previous
//
#include <hip/hip_runtime.h>
#include <hip/hip_bf16.h>

// ---------------------------------------------------------------------------
// CorrectTransformerAdaptor — Round 13: deep-pipeline GEMM + attn setprio.
//   Round-8 evidence: 2-deep dbuf + vmcnt(3) was ~neutral — prefetch lead
//   (1 compute phase ~150cy) << load latency (200-900cy).
//   - gemm256: 3-deep LDS ring (72KB, 2 blocks/CU), 2-tile prefetch lead,
//     ONE barrier/K-step. Per iter: vmcnt(3) -> s_barrier -> issue t+2 ->
//     compute t. Write-hazard safe: buf[(t+2)%3]==buf[(t-1)%3] and the
//     barrier certifies all waves past compute t-1. Last iter vmcnt(0).
//     Staging/read swizzle pair unchanged from round 8 (refcheck-passed).
//   - attn: T5 s_setprio(1/0) around QK and PV MFMA clusters (m191 +4-7%).
//   - everything else unchanged from round 8 (844 µs, passing).
// ---------------------------------------------------------------------------

#define DMODEL 1024
#define DFF 2048
#define FHID 256
#define NHEAD 8
#define DKH 128
#define TSEQ 1024

typedef __hip_bfloat16 bf16;
typedef __attribute__((ext_vector_type(8))) short bf16x8;   // 8 bf16 = 4 VGPR
typedef __attribute__((ext_vector_type(4))) float f32x4;

#define MFMA16(a, b, c) __builtin_amdgcn_mfma_f32_16x16x32_bf16(a, b, c, 0, 0, 0)

__device__ int g_is_bf16;

// one coherent load per block, broadcast via LDS (needs all threads at entry)
__device__ __forceinline__ bool flagbf_block() {
    __shared__ int fsh;
    if (threadIdx.x == 0)
        fsh = __hip_atomic_load(&g_is_bf16, __ATOMIC_ACQUIRE,
                                __HIP_MEMORY_SCOPE_AGENT);
    __syncthreads();
    return fsh != 0;
}
__device__ __forceinline__ float gload(const void* p, size_t i, bool bf) {
    return bf ? __bfloat162float(((const bf16*)p)[i]) : ((const float*)p)[i];
}
__device__ __forceinline__ void gstore(void* p, size_t i, bool bf, float v) {
    if (bf) ((bf16*)p)[i] = __float2bfloat16(v);
    else    ((float*)p)[i] = v;
}

// direct global->LDS, 16 bytes/lane. LDS base must be wave-uniform (m104);
// lane writes at base + lane*16. Global address is per-lane.
__device__ __forceinline__ void async16(const bf16* g, const bf16* l) {
    __builtin_amdgcn_global_load_lds(
        (const __attribute__((address_space(1))) void*)g,
        (__attribute__((address_space(3))) void*)l, 16, 0, 0);
}

// ---- dtype probe (64 lanes, ballot) ---------------------------------------
__global__ void detect_kernel(const void* __restrict__ probe) {
    const int lane = threadIdx.x & 63;
    const bf16* h = (const bf16*)probe;
    int ok = 1;
    #pragma unroll
    for (int j = 0; j < 4; ++j) {
        float v = __bfloat162float(h[lane * 4 + j]);
        if (!(fabsf(v) <= 1000.0f)) ok = 0;   // catches huge AND NaN
    }
    unsigned long long m = __ballot(ok);
    if (lane == 0)
        __hip_atomic_store(&g_is_bf16, m == ~0ull ? 1 : 0, __ATOMIC_RELEASE,
                           __HIP_MEMORY_SCOPE_AGENT);
}

// ---- weight arena offsets (bf16 elems) — fp32-input path only -------------
#define O_W1  0ull
#define O_W2  2097152ull
#define O_QK  4194304ull
#define O_WV  8388608ull
#define O_WO  10485760ull
#define O_F1  12582912ull
#define O_F2  13107200ull
#define ARENA_ELEMS 13631488ull

// one block = 16384 elems; per iteration a wave does unit-stride float4
// reads (1KB/instr) and unit-stride uint2 bf16 writes (512B/instr).
__global__ __launch_bounds__(256) void cvt_weights(
        const void* W1, const void* W2, const void* Wq, const void* Wk,
        const void* Wv, const void* Wo, const void* F1, const void* F2,
        bf16* __restrict__ arena) {
    if (flagbf_block()) return;   // bf16 inputs: GEMMs read them directly
    int b = blockIdx.x;
    const float* src; bf16* dst;
    if      (b < 128)  {           src = (const float*)W1 + (size_t)b * 16384;
                         dst = arena + O_W1 + (size_t)b * 16384; }
    else if (b < 256)  { b -= 128; src = (const float*)W2 + (size_t)b * 16384;
                         dst = arena + O_W2 + (size_t)b * 16384; }
    else if (b < 384)  { b -= 256; src = (const float*)Wq + (size_t)b * 16384;
                         dst = arena + O_QK + (size_t)(b >> 6) * 2097152
                                            + (size_t)(b & 63) * 16384; }
    else if (b < 512)  { b -= 384; src = (const float*)Wk + (size_t)b * 16384;
                         dst = arena + O_QK + (size_t)(b >> 6) * 2097152
                                            + 1048576 + (size_t)(b & 63) * 16384; }
    else if (b < 640)  { b -= 512; src = (const float*)Wv + (size_t)b * 16384;
                         dst = arena + O_WV + (size_t)b * 16384; }
    else if (b < 768)  { b -= 640; src = (const float*)Wo + (size_t)b * 16384;
                         dst = arena + O_WO + (size_t)b * 16384; }
    else if (b < 800)  { b -= 768; src = (const float*)F1 + (size_t)b * 16384;
                         dst = arena + O_F1 + (size_t)b * 16384; }
    else               { b -= 800; src = (const float*)F2 + (size_t)b * 16384;
                         dst = arena + O_F2 + (size_t)b * 16384; }
    const int tid = threadIdx.x;
    #pragma unroll
    for (int it = 0; it < 16; ++it) {
        const int e = it * 1024 + tid * 4;
        float4 f = *(const float4*)(src + e);
        bf16 t[4] = {__float2bfloat16(f.x), __float2bfloat16(f.y),
                     __float2bfloat16(f.z), __float2bfloat16(f.w)};
        *(uint2*)(dst + e) = *(const uint2*)t;
    }
}

__global__ __launch_bounds__(256) void cvt_x(
        const void* __restrict__ X, size_t x_off, bf16* __restrict__ dst) {
    if (flagbf_block()) return;   // bf16 x is consumed in place
    const float* src = (const float*)X + x_off + (size_t)blockIdx.x * 16384;
    bf16* d = dst + (size_t)blockIdx.x * 16384;
    const int tid = threadIdx.x;
    #pragma unroll
    for (int it = 0; it < 16; ++it) {
        const int e = it * 1024 + tid * 4;
        float4 f = *(const float4*)(src + e);
        bf16 t[4] = {__float2bfloat16(f.x), __float2bfloat16(f.y),
                     __float2bfloat16(f.z), __float2bfloat16(f.w)};
        *(uint2*)(d + e) = *(const uint2*)t;
    }
}

// ---------------- 256x128 3-deep pipelined GEMM ----------------------------
// 512 thr = 8 waves (4M x 2N), per-wave 64x64 out, BK=32, LDS ring depth 3
// (72KB -> 2 blocks/CU). Per iter: vmcnt(3) -> s_barrier -> issue tile t+2
// -> compute tile t. One barrier per K-step; 2-tile prefetch lead.
template <bool RELU, bool ADD, int CMODE, bool TRANSC, bool BIAS2>
__global__ __launch_bounds__(512, 4) void gemm256(
        const bf16* Abf, const bf16* Acv,
        const bf16* Wlo_bf, const bf16* Whi_bf,
        const bf16* Wlo_cv, const bf16* Whi_cv,
        const void* __restrict__ bias, const void* __restrict__ bias2,
        size_t b_off,
        void* __restrict__ C, size_t c_off,
        int M, int N, int K) {
    const bool fl = flagbf_block();
    const bf16* A   = fl ? Abf : Acv;
    const bf16* Wlo = fl ? Wlo_bf : Wlo_cv;
    const bf16* Whi = fl ? Whi_bf : Whi_cv;

    __shared__ __align__(16) bf16 As[3][256 * 32];   // 48 KB
    __shared__ __align__(16) bf16 Bs[3][128 * 32];   // 24 KB

    // XCD band remap over (gx = N/128, gy = M/256)
    const int gx = gridDim.x;
    const int lin = blockIdx.x + gx * blockIdx.y;
    int bm, bn;
    if ((gridDim.y & 7) == 0) {
        const int xcd = lin & 7, j = lin >> 3;
        const int rpx = gridDim.y >> 3;
        bm = (xcd * rpx + (j / gx)) * 256;
        bn = (j % gx) * 128;
    } else {
        bm = blockIdx.y * 256;
        bn = blockIdx.x * 128;
    }

    const int tid = threadIdx.x;
    const int wave = tid >> 6, lane = tid & 63;
    const int quad = lane >> 4, l15 = lane & 15;
    const int wm = wave >> 1, wn = wave & 1;

    const bf16* Wp;
    int bnr;
    if (BIAS2 && bn >= 1024) { Wp = Whi; bnr = bn - 1024; }
    else                     { Wp = Wlo; bnr = bn; }

    // staging: lane covers row lane>>2 (of 16), chunk lane&3; source chunk
    // pre-swizzled by ((row>>1)&3) == ((lane>>3)&3) for 16-aligned bases.
    const int srow = lane >> 2;
    const int schunk = (lane & 3) ^ ((lane >> 3) & 3);
    const bf16* gaBase = A  + (size_t)(bm  + wave * 32 + srow) * K + schunk * 8;
    const bf16* gbBase = Wp + (size_t)(bnr + wave * 16 + srow) * K + schunk * 8;
    const int laOff0 = (wave * 32) * 32;
    const int laOff1 = (wave * 32 + 16) * 32;
    const int lbOff  = (wave * 16) * 32;

    f32x4 acc[4][4];
    #pragma unroll
    for (int i = 0; i < 4; ++i)
        #pragma unroll
        for (int j = 0; j < 4; ++j) acc[i][j] = (f32x4){0.f, 0.f, 0.f, 0.f};

    const int nt = K >> 5;       // >= 32 for all our shapes

    // prologue: stage tiles 0 and 1 (6 loads in flight)
    async16(gaBase, &As[0][laOff0]);
    async16(gaBase + (size_t)16 * K, &As[0][laOff1]);
    async16(gbBase, &Bs[0][lbOff]);
    async16(gaBase + 32, &As[1][laOff0]);
    async16(gaBase + (size_t)16 * K + 32, &As[1][laOff1]);
    async16(gbBase + 32, &Bs[1][lbOff]);

    int cur = 0;
    for (int t = 0; t < nt; ++t) {
        // drain OWN tile-t loads (tile t+1's 3 stay in flight), then barrier:
        // after it, tile t is globally visible and every wave is past its
        // compute of t-1 (so buf[(t+2)%3] == buf[(t-1)%3] is reusable).
        if (t == nt - 1) {
            __asm__ __volatile__("s_waitcnt vmcnt(0)" ::: "memory");
        } else {
            __asm__ __volatile__("s_waitcnt vmcnt(3)" ::: "memory");
        }
        __builtin_amdgcn_s_barrier();
        __builtin_amdgcn_sched_barrier(0);

        if (t + 2 < nt) {                       // prefetch tile t+2
            int pf = cur + 2; if (pf >= 3) pf -= 3;
            const int kn = (t + 2) << 5;
            async16(gaBase + kn, &As[pf][laOff0]);
            async16(gaBase + (size_t)16 * K + kn, &As[pf][laOff1]);
            async16(gbBase + kn, &Bs[pf][lbOff]);
        }

        // compute tile t from buf[cur]
        bf16x8 bfr[4];
        #pragma unroll
        for (int ni = 0; ni < 4; ++ni) {
            const int row = wn * 64 + ni * 16 + l15;
            bfr[ni] = *(const bf16x8*)
                &Bs[cur][row * 32 + ((quad ^ ((row >> 1) & 3)) << 3)];
        }
        #pragma unroll
        for (int mi = 0; mi < 4; ++mi) {
            const int row = wm * 64 + mi * 16 + l15;
            bf16x8 af = *(const bf16x8*)
                &As[cur][row * 32 + ((quad ^ ((row >> 1) & 3)) << 3)];
            #pragma unroll
            for (int ni = 0; ni < 4; ++ni)
                acc[mi][ni] = MFMA16(af, bfr[ni], acc[mi][ni]);
        }
        cur = (cur == 2) ? 0 : cur + 1;
    }

    // epilogue: acc row = quad*4+rr, col = lane&15 (verified m89/m91 layout)
    const bool cbf = CMODE ? fl : true;
    #pragma unroll
    for (int ni = 0; ni < 4; ++ni) {
        const int col = bn + wn * 64 + ni * 16 + l15;
        float bv;
        if (BIAS2) bv = col < 1024 ? gload(bias, b_off + col, fl)
                                   : gload(bias2, b_off + col - 1024, fl);
        else       bv = gload(bias, b_off + col, fl);
        #pragma unroll
        for (int mi = 0; mi < 4; ++mi) {
            const int row0 = bm + wm * 64 + mi * 16 + quad * 4;
            if (TRANSC) {
                bf16 pk[4];
                #pragma unroll
                for (int rr = 0; rr < 4; ++rr)
                    pk[rr] = __float2bfloat16(acc[mi][ni][rr] + bv);
                *(uint2*)((bf16*)C + c_off + (size_t)col * M + row0) =
                    *(const uint2*)pk;
            } else {
                #pragma unroll
                for (int rr = 0; rr < 4; ++rr) {
                    float v = acc[mi][ni][rr] + bv;
                    if (RELU) v = fmaxf(v, 0.f);
                    size_t idx = c_off + (size_t)(row0 + rr) * N + col;
                    if (ADD) v += gload(C, idx, cbf);
                    gstore(C, idx, cbf, v);
                }
            }
        }
    }
}

// ---------------- 128x128 m97 GEMM (kept for F1/F2) ------------------------
template <bool RELU, bool ADD, int CMODE, bool TRANSC, bool BIAS2>
__global__ __launch_bounds__(256) void gemm_bf16(
        const bf16* Abf, const bf16* Acv,
        const bf16* Wlo_bf, const bf16* Whi_bf,
        const bf16* Wlo_cv, const bf16* Whi_cv,
        const void* __restrict__ bias, const void* __restrict__ bias2,
        size_t b_off,
        void* __restrict__ C, size_t c_off,
        int M, int N, int K) {
    const bool fl = flagbf_block();
    const bf16* A   = fl ? Abf : Acv;
    const bf16* Wlo = fl ? Wlo_bf : Wlo_cv;
    const bf16* Whi = fl ? Whi_bf : Whi_cv;

    __shared__ __align__(16) bf16 As[128 * 64];
    __shared__ __align__(16) bf16 Bs[128 * 64];

    const int gx = gridDim.x;
    const int lin = blockIdx.x + gx * blockIdx.y;
    int bm, bn;
    if ((gridDim.y & 7) == 0) {
        const int xcd = lin & 7, j = lin >> 3;
        const int rpx = gridDim.y >> 3;
        bm = (xcd * rpx + j / gx) * 128;
        bn = (j % gx) * 128;
    } else {
        bm = blockIdx.y * 128;
        bn = blockIdx.x * 128;
    }

    const int tid = threadIdx.x;
    const int wave = tid >> 6, lane = tid & 63;
    const int quad = lane >> 4, l15 = lane & 15;
    const int wr = wave >> 1, wc = wave & 1;
    const int l8 = lane >> 3, l7 = lane & 7;
    const int swz = l7 ^ l8;          // row&7 == l8 for our staging rows

    const bf16* Wp;
    int bnr;
    if (BIAS2 && bn >= 1024) { Wp = Whi; bnr = bn - 1024; }
    else                     { Wp = Wlo; bnr = bn; }

    f32x4 acc[4][4];
    #pragma unroll
    for (int i = 0; i < 4; ++i)
        #pragma unroll
        for (int j2 = 0; j2 < 4; ++j2) acc[i][j2] = (f32x4){0.f, 0.f, 0.f, 0.f};

    const bf16* ga0 = A  + (size_t)(bm  + wave * 32 + l8) * K + swz * 8;
    const bf16* gb0 = Wp + (size_t)(bnr + wave * 32 + l8) * K + swz * 8;
    bf16* la0 = &As[(wave * 32) * 64];
    bf16* lb0 = &Bs[(wave * 32) * 64];

    for (int k0 = 0; k0 < K; k0 += 64) {
        __syncthreads();
        #pragma unroll
        for (int i = 0; i < 4; ++i) {
            async16(ga0 + (size_t)(i * 8) * K + k0, la0 + i * 512);
            async16(gb0 + (size_t)(i * 8) * K + k0, lb0 + i * 512);
        }
        __syncthreads();

        #pragma unroll
        for (int ks = 0; ks < 2; ++ks) {
            bf16x8 af[4], bfr[4];
            #pragma unroll
            for (int mi = 0; mi < 4; ++mi) {
                const int row = wr * 64 + mi * 16 + l15;
                af[mi] = *(const bf16x8*)
                    &As[row * 64 + ((((ks << 2) | quad) ^ (row & 7)) << 3)];
            }
            #pragma unroll
            for (int ni = 0; ni < 4; ++ni) {
                const int row = wc * 64 + ni * 16 + l15;
                bfr[ni] = *(const bf16x8*)
                    &Bs[row * 64 + ((((ks << 2) | quad) ^ (row & 7)) << 3)];
            }
            #pragma unroll
            for (int mi = 0; mi < 4; ++mi)
                #pragma unroll
                for (int ni = 0; ni < 4; ++ni)
                    acc[mi][ni] = MFMA16(af[mi], bfr[ni], acc[mi][ni]);
        }
    }

    const bool cbf = CMODE ? fl : true;
    #pragma unroll
    for (int ni = 0; ni < 4; ++ni) {
        const int col = bn + wc * 64 + ni * 16 + l15;
        float bv;
        if (BIAS2) bv = col < 1024 ? gload(bias, b_off + col, fl)
                                   : gload(bias2, b_off + col - 1024, fl);
        else       bv = gload(bias, b_off + col, fl);
        #pragma unroll
        for (int mi = 0; mi < 4; ++mi) {
            const int row0 = bm + wr * 64 + mi * 16 + quad * 4;
            if (TRANSC) {
                bf16 pk[4];
                #pragma unroll
                for (int rr = 0; rr < 4; ++rr)
                    pk[rr] = __float2bfloat16(acc[mi][ni][rr] + bv);
                *(uint2*)((bf16*)C + c_off + (size_t)col * M + row0) =
                    *(const uint2*)pk;
            } else {
                #pragma unroll
                for (int rr = 0; rr < 4; ++rr) {
                    float v = acc[mi][ni][rr] + bv;
                    if (RELU) v = fmaxf(v, 0.f);
                    size_t idx = c_off + (size_t)(row0 + rr) * N + col;
                    if (ADD) v += gload(C, idx, cbf);
                    gstore(C, idx, cbf, v);
                }
            }
        }
    }
}

// ---------------- LayerNorm: one wave per row, shuffle-only ----------------
__global__ __launch_bounds__(256) void ln_wave(
        const void* __restrict__ X, size_t x_off,
        const void* __restrict__ g, const void* __restrict__ b, size_t gb_off,
        bf16* __restrict__ H) {
    const bool fl = flagbf_block();
    const int lane = threadIdx.x & 63;
    const int row = blockIdx.x * 4 + (threadIdx.x >> 6);
    const size_t xrow = x_off + (size_t)row * DMODEL;

    float v[16];
    if (fl) {
        const bf16* xp = (const bf16*)X + xrow;
        #pragma unroll
        for (int c = 0; c < 2; ++c) {
            uint4 raw = *(const uint4*)(xp + c * 512 + lane * 8);
            const bf16* rb = (const bf16*)&raw;
            #pragma unroll
            for (int j = 0; j < 8; ++j) v[c * 8 + j] = __bfloat162float(rb[j]);
        }
    } else {
        const float* xp = (const float*)X + xrow;
        #pragma unroll
        for (int c = 0; c < 4; ++c) {
            float4 f = *(const float4*)(xp + c * 256 + lane * 4);
            v[c * 4 + 0] = f.x; v[c * 4 + 1] = f.y;
            v[c * 4 + 2] = f.z; v[c * 4 + 3] = f.w;
        }
    }

    float s = 0.f;
    #pragma unroll
    for (int j = 0; j < 16; ++j) s += v[j];
    #pragma unroll
    for (int off = 32; off > 0; off >>= 1) s += __shfl_xor(s, off);
    const float mean = s * (1.f / DMODEL);

    float vs = 0.f;
    #pragma unroll
    for (int j = 0; j < 16; ++j) { float d = v[j] - mean; vs += d * d; }
    #pragma unroll
    for (int off = 32; off > 0; off >>= 1) vs += __shfl_xor(vs, off);
    const float rstd = rsqrtf(vs * (1.f / DMODEL) + 1e-12f);

    bf16* h = H + (size_t)row * DMODEL;
    if (fl) {
        const bf16* gp = (const bf16*)g + gb_off;
        const bf16* bp = (const bf16*)b + gb_off;
        #pragma unroll
        for (int c = 0; c < 2; ++c) {
            const int o = c * 512 + lane * 8;
            uint4 gr = *(const uint4*)(gp + o);
            uint4 br = *(const uint4*)(bp + o);
            const bf16* gg = (const bf16*)&gr;
            const bf16* bb = (const bf16*)&br;
            bf16 outv[8];
            #pragma unroll
            for (int j = 0; j < 8; ++j)
                outv[j] = __float2bfloat16((v[c * 8 + j] - mean) * rstd *
                          __bfloat162float(gg[j]) + __bfloat162float(bb[j]));
            *(uint4*)(h + o) = *(const uint4*)outv;
        }
    } else {
        const float* gp = (const float*)g + gb_off;
        const float* bp = (const float*)b + gb_off;
        #pragma unroll
        for (int c = 0; c < 4; ++c) {
            const int o = c * 256 + lane * 4;
            float4 gr = *(const float4*)(gp + o);
            float4 br = *(const float4*)(bp + o);
            const float gg[4] = {gr.x, gr.y, gr.z, gr.w};
            const float bb[4] = {br.x, br.y, br.z, br.w};
            bf16 outv[4];
            #pragma unroll
            for (int j = 0; j < 4; ++j)
                outv[j] = __float2bfloat16((v[c * 4 + j] - mean) * rstd * gg[j] + bb[j]);
            *(uint2*)(h + o) = *(const uint2*)outv;
        }
    }
}

// ---------------- Flash-style MFMA attention -------------------------------
// Grid: (TSEQ/128, NHEAD, c). Block: 512 threads = 8 waves, wave w owns
// q-rows [qt*128 + w*16, +16). K loop over 64-key tiles staged in LDS.
// XCD swizzle: each XCD owns whole (bb, all-head) groups. T13 defer-rescale.
// T5: setprio(1) around the QK and PV MFMA clusters.
__global__ __launch_bounds__(512) void attn_mfma(
        const bf16* __restrict__ QK, const bf16* __restrict__ Vg,
        bf16* __restrict__ Om) {
    const int cch = (int)gridDim.z;                  // chunk count c
    const int lin = blockIdx.x + (int)gridDim.x *
                    (blockIdx.y + (int)gridDim.y * blockIdx.z);
    const int xcd = lin & 7, j = lin >> 3;           // 64c blocks, div by 8
    const int qt = j & 7, gl = j >> 3;               // gl in [0,c)
    const int g = xcd * cch + gl;                    // (h,bb) group id
    const int h = g & 7, bb = g >> 3;

    const int Mc = cch * TSEQ;
    const int tid = threadIdx.x;
    const int wave = tid >> 6, lane = tid & 63;
    const int quad = lane >> 4, l15 = lane & 15;

    __shared__ __align__(16) bf16 Kt[64][128];
    __shared__ __align__(16) bf16 Vt[128][64];
    __shared__ __align__(16) bf16 Ps[8][16][72];

    const int qrow = qt * 128 + wave * 16 + l15;
    const float scale = 0.08838834764831845f;  // 1/sqrt(128)

    bf16x8 qf[4];
    #pragma unroll
    for (int kc = 0; kc < 4; ++kc) {
        uint4 raw = *(const uint4*)(QK + (size_t)(bb * TSEQ + qrow) * 2048 +
                                    h * DKH + kc * 32 + quad * 8);
        const bf16* rb = (const bf16*)&raw;
        bf16 tmp[8];
        #pragma unroll
        for (int j2 = 0; j2 < 8; ++j2)
            tmp[j2] = __float2bfloat16(__bfloat162float(rb[j2]) * scale);
        qf[kc] = *(const bf16x8*)tmp;
    }

    f32x4 o[8];
    #pragma unroll
    for (int i = 0; i < 8; ++i) o[i] = (f32x4){0.f, 0.f, 0.f, 0.f};
    float m_i[4] = {-1e30f, -1e30f, -1e30f, -1e30f};
    float l_i[4] = {0.f, 0.f, 0.f, 0.f};

    const int skey = tid >> 3;              // K staging: row = key (0..63)
    const int dseg = (tid & 7) * 16;        // 2 x uint4 per thread
    const int sk7 = skey & 7;
    const int vd = tid >> 2;                // V staging: row = d (0..127)
    const int vseg = (tid & 3) * 16;        // 2 x uint4 per thread

    for (int kt = 0; kt < TSEQ / 64; ++kt) {
        __syncthreads();
        {
            const bf16* kp = QK + (size_t)(bb * TSEQ + kt * 64 + skey) * 2048 +
                             1024 + h * DKH + dseg;
            const bf16* vp = Vg + (size_t)(h * DKH + vd) * Mc + bb * TSEQ +
                             kt * 64 + vseg;
            uint4 kv[2], vv[2];
            #pragma unroll
            for (int g2 = 0; g2 < 2; ++g2) { kv[g2] = ((const uint4*)kp)[g2]; vv[g2] = ((const uint4*)vp)[g2]; }
            #pragma unroll
            for (int g2 = 0; g2 < 2; ++g2) {
                int c = (dseg >> 3) + g2;
                *(uint4*)&Kt[skey][(c ^ sk7) << 3] = kv[g2];
            }
            #pragma unroll
            for (int g2 = 0; g2 < 2; ++g2) {
                int c = (vseg >> 3) + g2;
                *(uint4*)&Vt[vd][(c ^ (vd & 7)) << 3] = vv[g2];
            }
        }
        __syncthreads();

        f32x4 s[4];
        #pragma unroll
        for (int ni = 0; ni < 4; ++ni) s[ni] = (f32x4){0.f, 0.f, 0.f, 0.f};
        __builtin_amdgcn_s_setprio(1);
        #pragma unroll
        for (int ni = 0; ni < 4; ++ni) {
            const int key = ni * 16 + l15;
            #pragma unroll
            for (int kc = 0; kc < 4; ++kc) {
                const int d3 = kc * 4 + quad;
                bf16x8 kb = *(const bf16x8*)&Kt[key][(d3 ^ (key & 7)) << 3];
                s[ni] = MFMA16(qf[kc], kb, s[ni]);
            }
        }
        __builtin_amdgcn_s_setprio(0);

        float tm[4], ts[4];
        #pragma unroll
        for (int rr = 0; rr < 4; ++rr) {
            float v = fmaxf(fmaxf(s[0][rr], s[1][rr]), fmaxf(s[2][rr], s[3][rr]));
            v = fmaxf(v, __shfl_xor(v, 1));
            v = fmaxf(v, __shfl_xor(v, 2));
            v = fmaxf(v, __shfl_xor(v, 4));
            v = fmaxf(v, __shfl_xor(v, 8));
            tm[rr] = v;
        }
        // T13: only rescale when the running max grows by > 8 (wave-uniform)
        int grow = 0;
        #pragma unroll
        for (int rr = 0; rr < 4; ++rr)
            grow |= (tm[rr] > m_i[rr] + 8.f) ? 1 : 0;
        if (__any(grow)) {
            float al[4];
            #pragma unroll
            for (int rr = 0; rr < 4; ++rr) {
                float mn = fmaxf(m_i[rr], tm[rr]);
                al[rr] = __expf(m_i[rr] - mn);
                m_i[rr] = mn;
                l_i[rr] *= al[rr];
            }
            #pragma unroll
            for (int i = 0; i < 8; ++i)
                #pragma unroll
                for (int rr = 0; rr < 4; ++rr) o[i][rr] *= al[rr];
        }
        #pragma unroll
        for (int rr = 0; rr < 4; ++rr) ts[rr] = 0.f;
        #pragma unroll
        for (int ni = 0; ni < 4; ++ni)
            #pragma unroll
            for (int rr = 0; rr < 4; ++rr) {
                float p = __expf(s[ni][rr] - m_i[rr]);
                s[ni][rr] = p;
                ts[rr] += p;
            }
        #pragma unroll
        for (int rr = 0; rr < 4; ++rr) {
            float v = ts[rr];
            v += __shfl_xor(v, 1);
            v += __shfl_xor(v, 2);
            v += __shfl_xor(v, 4);
            v += __shfl_xor(v, 8);
            l_i[rr] += v;
        }

        #pragma unroll
        for (int ni = 0; ni < 4; ++ni)
            #pragma unroll
            for (int rr = 0; rr < 4; ++rr)
                Ps[wave][quad * 4 + rr][ni * 16 + l15] = __float2bfloat16(s[ni][rr]);
        __asm__ __volatile__("s_waitcnt lgkmcnt(0)" ::: "memory");
        bf16x8 pa[2];
        #pragma unroll
        for (int kc2 = 0; kc2 < 2; ++kc2)
            pa[kc2] = *(const bf16x8*)&Ps[wave][l15][kc2 * 32 + quad * 8];

        __builtin_amdgcn_s_setprio(1);
        #pragma unroll
        for (int ni2 = 0; ni2 < 8; ++ni2) {
            const int d = ni2 * 16 + l15;
            #pragma unroll
            for (int kc2 = 0; kc2 < 2; ++kc2) {
                const int key3 = kc2 * 4 + quad;
                bf16x8 vb = *(const bf16x8*)&Vt[d][(key3 ^ (d & 7)) << 3];
                o[ni2] = MFMA16(pa[kc2], vb, o[ni2]);
            }
        }
        __builtin_amdgcn_s_setprio(0);
    }

    float rinv[4];
    #pragma unroll
    for (int rr = 0; rr < 4; ++rr) rinv[rr] = 1.0f / l_i[rr];
    const size_t obase = (size_t)bb * TSEQ * DMODEL + (size_t)h * DKH;
    #pragma unroll
    for (int ni2 = 0; ni2 < 8; ++ni2)
        #pragma unroll
        for (int rr = 0; rr < 4; ++rr) {
            int qr = qt * 128 + wave * 16 + quad * 4 + rr;
            Om[obase + (size_t)qr * DMODEL + ni2 * 16 + l15] =
                __float2bfloat16(o[ni2][rr] * rinv[rr]);
        }
}

// ---------------------------------------------------------------------------
extern "C" void kernel_launch(void* const* d_in, const int* in_sizes, int n_in,
                              void* d_out, int out_size, void* d_ws, size_t ws_size,
                              hipStream_t stream) {
    const void* x     = d_in[0];
    const void* W1    = d_in[1];
    const void* b1    = d_in[2];
    const void* W2    = d_in[3];
    const void* b2    = d_in[4];
    const void* ln1_g = d_in[5];
    const void* ln1_b = d_in[6];
    const void* ln2_g = d_in[7];
    const void* ln2_b = d_in[8];
    const void* Wq    = d_in[9];
    const void* bq    = d_in[10];
    const void* Wk    = d_in[11];
    const void* bk    = d_in[12];
    const void* Wv    = d_in[13];
    const void* bv    = d_in[14];
    const void* Wo    = d_in[15];
    const void* bo    = d_in[16];
    const void* Fw1   = d_in[17];
    const void* Fb1   = d_in[18];
    const void* Fw2   = d_in[19];
    const void* Fb2   = d_in[20];

    detect_kernel<<<1, 64, 0, stream>>>(W1);

    // workspace: [Hh | QKb | Vtb | Xc | weight arena], all bf16
    int c = 8;
    while (c > 1 &&
           (5ull * (size_t)c * (1ull << 20) + ARENA_ELEMS) * 2ull > ws_size)
        c >>= 1;
    const int nch = 8 / c;
    const int Mc = c * TSEQ;
    const size_t SL = (size_t)Mc * DMODEL;

    bf16* Hh  = (bf16*)d_ws;      // Mc x 1024
    bf16* QKb = Hh + SL;          // Mc x 2048 (fused Q|K)
    bf16* Vtb = QKb + 2 * SL;     // 1024 x Mc (V^T)
    bf16* Xc  = Vtb + SL;         // Mc x 1024 (fp32-input path only)
    bf16* Wt  = Xc + SL;          // weight arena (fp32-input path only)
    bf16* Hid = QKb;              // Mc x 2048 scratch (downsample hidden)
    bf16* Ffh = QKb;              // Mc x 256 scratch (FFN hidden)
    bf16* Ob  = Hh;               // attn output reuses LN buffer
    void* X = d_out;              // residual stream (flag dtype)

    const bf16* xb  = (const bf16*)x;
    bf16* cW1  = Wt + O_W1;
    bf16* cW2  = Wt + O_W2;
    bf16* cWqk = Wt + O_QK;
    bf16* cWv  = Wt + O_WV;
    bf16* cWo  = Wt + O_WO;
    bf16* cF1  = Wt + O_F1;
    bf16* cF2  = Wt + O_F2;

    cvt_weights<<<832, 256, 0, stream>>>(W1, W2, Wq, Wk, Wv, Wo, Fw1, Fw2, Wt);

    for (int ci = 0; ci < nch; ++ci) {
        const size_t roff = (size_t)ci * Mc * DMODEL;

        cvt_x<<<(int)(SL / 16384), 256, 0, stream>>>(x, roff, Xc);

        gemm256<true, false, 0, false, false><<<dim3(DFF / 128, Mc / 256), 512, 0, stream>>>(
            xb + roff, Xc, (const bf16*)W1, (const bf16*)W1, cW1, cW1,
            b1, nullptr, 0, Hid, 0, Mc, DFF, DMODEL);
        gemm256<false, false, 1, false, false><<<dim3(DMODEL / 128, Mc / 256), 512, 0, stream>>>(
            Hid, Hid, (const bf16*)W2, (const bf16*)W2, cW2, cW2,
            b2, nullptr, 0, X, roff, Mc, DMODEL, DFF);

        for (int l = 0; l < 2; ++l) {
            const size_t wOff   = (size_t)l * DMODEL * DMODEL;       // 1M
            const size_t fOff   = (size_t)l * FHID * DMODEL;         // 256K
            const size_t vOff   = (size_t)l * DMODEL;
            const size_t f1bOff = (size_t)l * FHID;

            const bf16* wqL = (const bf16*)Wq + wOff;
            const bf16* wkL = (const bf16*)Wk + wOff;
            const bf16* wvL = (const bf16*)Wv + wOff;
            const bf16* woL = (const bf16*)Wo + wOff;
            const bf16* f1L = (const bf16*)Fw1 + fOff;
            const bf16* f2L = (const bf16*)Fw2 + fOff;
            const bf16* qkLo = cWqk + (size_t)l * 2097152;
            const bf16* qkHi = qkLo + 1048576;

            ln_wave<<<Mc / 4, 256, 0, stream>>>(X, roff, ln1_g, ln1_b, vOff, Hh);
            // fused Q|K GEMM: N=2048, weight/bias select at col 1024 (uniform)
            gemm256<false, false, 0, false, true><<<dim3(2048 / 128, Mc / 256), 512, 0, stream>>>(
                Hh, Hh, wqL, wkL, qkLo, qkHi,
                bq, bk, vOff, QKb, 0, Mc, 2048, DMODEL);
            // V GEMM with transposed store -> Vtb = V^T [1024][Mc]
            gemm256<false, false, 0, true, false><<<dim3(DMODEL / 128, Mc / 256), 512, 0, stream>>>(
                Hh, Hh, wvL, wvL, cWv + wOff, cWv + wOff,
                bv, nullptr, vOff, Vtb, 0, Mc, DMODEL, DMODEL);

            attn_mfma<<<dim3(TSEQ / 128, NHEAD, c), 512, 0, stream>>>(QKb, Vtb, Ob);

            gemm256<false, true, 1, false, false><<<dim3(DMODEL / 128, Mc / 256), 512, 0, stream>>>(
                Ob, Ob, woL, woL, cWo + wOff, cWo + wOff,
                bo, nullptr, vOff, X, roff, Mc, DMODEL, DMODEL);

            ln_wave<<<Mc / 4, 256, 0, stream>>>(X, roff, ln2_g, ln2_b, vOff, Hh);
            gemm_bf16<true, false, 0, false, false><<<dim3(FHID / 128, Mc / 128), 256, 0, stream>>>(
                Hh, Hh, f1L, f1L, cF1 + fOff, cF1 + fOff,
                Fb1, nullptr, f1bOff, Ffh, 0, Mc, FHID, DMODEL);
            gemm_bf16<false, true, 1, false, false><<<dim3(DMODEL / 128, Mc / 128), 256, 0, stream>>>(
                Ffh, Ffh, f2L, f2L, cF2 + fOff, cF2 + fOff,
                Fb2, nullptr, vOff, X, roff, Mc, DMODEL, FHID);
        }
    }
}